// Round 17
// baseline (231.708 us; speedup 1.0000x reference)
//
#include <hip/hip_runtime.h>
#include <math.h>

#define N_NODES 20000
#define N_EDGES 320000
#define SK 20480   // zero-padded K (rows) for transposed gram operand
#define GPITCH 144 // gram LDS pitch (elems): 72 words % 32 == 8
#define KVROW 768  // kv row bytes: [k fp8 256B][v bf16 512B]
#define SP 68      // gemm epilogue stage pitch (floats): conflict-free writes

typedef short short8 __attribute__((ext_vector_type(8)));
typedef float f32x4 __attribute__((ext_vector_type(4)));
typedef float f32x2 __attribute__((ext_vector_type(2)));

static __device__ __forceinline__ unsigned short f2bf(float f) {
    unsigned int u = __float_as_uint(f);
    u = (u + 0x7FFF + ((u >> 16) & 1)) >> 16;
    return (unsigned short)u;
}
static __device__ __forceinline__ float b2f(unsigned short u) {
    return __uint_as_float((unsigned int)u << 16);
}

// ---------------- fused prep: conv_x (2500) | conv_w (1024) | zero deg (79) ----------------
__global__ __launch_bounds__(256) void prep_k(const float* __restrict__ x,
                                              unsigned short* __restrict__ xb,
                                              const float* __restrict__ Wq,
                                              const float* __restrict__ Wk,
                                              const float* __restrict__ Wv,
                                              const float* __restrict__ Wsk,
                                              const float* __restrict__ bq,
                                              const float* __restrict__ bk,
                                              const float* __restrict__ bv,
                                              const float* __restrict__ bsk,
                                              unsigned short* __restrict__ wT,
                                              float* __restrict__ bias_all,
                                              int* __restrict__ deg)
{
    const int b = blockIdx.x;
    const int tid = threadIdx.x;
    if (b < 2500) {
        const size_t base = ((size_t)b * 256 + tid) * 8;
        const float4 f0 = *(const float4*)(x + base);
        const float4 f1 = *(const float4*)(x + base + 4);
        ushort4 u0, u1;
        u0.x = f2bf(f0.x); u0.y = f2bf(f0.y); u0.z = f2bf(f0.z); u0.w = f2bf(f0.w);
        u1.x = f2bf(f1.x); u1.y = f2bf(f1.y); u1.z = f2bf(f1.z); u1.w = f2bf(f1.w);
        *(ushort4*)(xb + base) = u0;
        *(ushort4*)(xb + base + 4) = u1;
    } else if (b < 3524) {
        const int bb = b - 2500;               // 0..1023 : wi*256 + n
        const int wi = bb >> 8, n = bb & 255;
        const float* W = (wi == 0) ? Wq : (wi == 1) ? Wk : (wi == 2) ? Wv : Wsk;
        wT[(size_t)bb * 256 + tid] = f2bf(W[(size_t)tid * 256 + n]);
        if (tid == 0) {
            const float* bv_ = (wi == 0) ? bq : (wi == 1) ? bk : (wi == 2) ? bv : bsk;
            bias_all[bb] = bv_[n];
        }
    } else {
        const int i = (b - 3524) * 256 + tid;
        if (i < N_NODES) deg[i] = 0;
    }
}

// ---------------- fused QKVS GEMM: barrier-free, direct-from-global fragments ----------------
// grid (157, 9): by 0..7 = gemm planes (col base by*128); by==8 = count_deg plane
__global__ __launch_bounds__(256, 2) void gemm_qkvs(const unsigned short* __restrict__ xb,
                                                    const unsigned short* __restrict__ wT,
                                                    const float* __restrict__ bias_all,
                                                    unsigned short* __restrict__ qb,
                                                    unsigned char* __restrict__ kvb,
                                                    unsigned short* __restrict__ ob,
                                                    const int* __restrict__ dst,
                                                    int* __restrict__ deg)
{
    const int tid  = threadIdx.x;
    const int by   = blockIdx.y;
    if (by == 8) {                     // degree count (deg zeroed by prep_k)
        for (int e = blockIdx.x * 256 + tid; e < N_EDGES; e += 157 * 256)
            atomicAdd(&deg[dst[e]], 1);
        return;
    }

    __shared__ float stage[4 * 16 * SP];   // wave-private 16x68 staging

    const int lane = tid & 63;
    const int w    = tid >> 6;         // 0..3
    const int wm = w >> 1, wn = w & 1; // wave grid 2x2 (64-row x 64-col per wave)
    const int row0 = blockIdx.x * 128;
    const int wsel = by >> 1;          // 0=q 1=k 2=v 3=skip
    const int chalf = by & 1;
    const int fr = lane & 15, fk = (lane >> 4) * 8, lg = lane >> 4;

    // per-fragment global row pointers (clamped tail rows; stores guarded)
    const unsigned short* ap[4];
    const unsigned short* bp[4];
#pragma unroll
    for (int m = 0; m < 4; ++m) {
        int r = row0 + wm * 64 + m * 16 + fr;
        r = r < N_NODES ? r : N_NODES - 1;
        ap[m] = xb + (size_t)r * 256 + fk;
    }
#pragma unroll
    for (int n = 0; n < 4; ++n)
        bp[n] = wT + (size_t)(by * 128 + wn * 64 + n * 16 + fr) * 256 + fk;

    f32x4 acc[4][4] = {};
#pragma unroll
    for (int ks = 0; ks < 8; ++ks) {
        short8 af[4], bf[4];
#pragma unroll
        for (int m = 0; m < 4; ++m) af[m] = *(const short8*)(ap[m] + ks * 32);
#pragma unroll
        for (int n = 0; n < 4; ++n) bf[n] = *(const short8*)(bp[n] + ks * 32);
#pragma unroll
        for (int m = 0; m < 4; ++m)
#pragma unroll
            for (int n = 0; n < 4; ++n)
                acc[m][n] = __builtin_amdgcn_mfma_f32_16x16x32_bf16(af[m], bf[n], acc[m][n], 0, 0, 0);
    }

    float badd[4];
#pragma unroll
    for (int n = 0; n < 4; ++n) badd[n] = bias_all[by * 128 + wn * 64 + n * 16 + fr];

    float* st = stage + w * (16 * SP);   // wave-private; no barriers needed
#pragma unroll
    for (int m = 0; m < 4; ++m) {
#pragma unroll
        for (int n = 0; n < 4; ++n)
#pragma unroll
            for (int r = 0; r < 4; ++r)
                st[(lg * 4 + r) * SP + n * 16 + fr] = acc[m][n][r] + badd[n];
#pragma unroll
        for (int it = 0; it < 4; ++it) {
            const int lrow = it * 4 + lg;
            const f32x4 c4 = *(const f32x4*)&st[lrow * SP + fr * 4];
            const int grow = row0 + wm * 64 + m * 16 + lrow;
            if (grow < N_NODES) {
                const int colin = chalf * 128 + wn * 64 + fr * 4;   // col within 256-wide output
                if (wsel == 1) {
                    int pk = __builtin_amdgcn_cvt_pk_fp8_f32(c4[0], c4[1], 0, false);
                    pk = __builtin_amdgcn_cvt_pk_fp8_f32(c4[2], c4[3], pk, true);
                    *(unsigned int*)(kvb + (size_t)grow * KVROW + colin) = (unsigned int)pk;
                } else {
                    ushort4 u;
                    u.x = f2bf(c4[0]); u.y = f2bf(c4[1]); u.z = f2bf(c4[2]); u.w = f2bf(c4[3]);
                    if (wsel == 3) {
                        *(ushort4*)(ob + (size_t)grow * 256 + colin) = u;
                    } else if (wsel == 0) {
                        *(ushort4*)(qb + (size_t)grow * 256 + colin) = u;
                    } else {
                        *(ushort4*)(kvb + (size_t)grow * KVROW + 256 + colin * 2) = u;
                    }
                }
            }
        }
    }
}

// ---------------- CSR scan (coalesced staging; also zeroes cursor) ----------------
__global__ __launch_bounds__(1024) void scan_k(const int* __restrict__ deg,
                                               int* __restrict__ row_start,
                                               int* __restrict__ cursor)
{
    __shared__ int sdeg[20480];          // 80 KB: coalesced staging
    const int tid = threadIdx.x;
    const int lane = tid & 63, wid = tid >> 6;
    const int CH = 20;
#pragma unroll
    for (int i = 0; i < 20; ++i) {
        const int idx = i * 1024 + tid;
        sdeg[idx] = (idx < N_NODES) ? deg[idx] : 0;
    }
    __syncthreads();
    const int base = tid * CH;
    int local[CH];
    int s = 0;
#pragma unroll
    for (int i = 0; i < CH; ++i) {
        local[i] = s;
        s += sdeg[base + i];
    }
    int v = s;
#pragma unroll
    for (int off = 1; off < 64; off <<= 1) {
        const int t = __shfl_up(v, off);
        if (lane >= off) v += t;
    }
    __shared__ int wsum[16];
    if (lane == 63) wsum[wid] = v;
    __syncthreads();
    if (tid == 0) {
        int r = 0;
        for (int i = 0; i < 16; ++i) { const int t = wsum[i]; wsum[i] = r; r += t; }
    }
    __syncthreads();
    const int excl = v - s + wsum[wid];
#pragma unroll
    for (int i = 0; i < CH; ++i) {
        const int idx = base + i;
        if (idx < N_NODES) {
            row_start[idx] = excl + local[i];
            cursor[idx] = 0;
        }
    }
    if (tid == 1023) row_start[N_NODES] = excl + s;
}

__global__ void fill_csr(const int* __restrict__ dst, const int* __restrict__ src,
                         const float* __restrict__ ea,
                         const int* __restrict__ row_start,
                         int* __restrict__ cursor, int2* __restrict__ ekv,
                         float* __restrict__ gstats)
{
    const int g = blockIdx.x * 256 + threadIdx.x;
    if (g < 512) gstats[g] = 0.f;          // zero stats for gn_stats_k (runs later)
    const int e = g;
    if (e < N_EDGES) {
        const int d = dst[e];
        const int p = atomicAdd(&cursor[d], 1);
        int2 pk;
        pk.x = src[e];
        pk.y = __float_as_int(ea[e]);
        ekv[row_start[d] + p] = pk;
    }
}

// ---------------- attention: single pass, fp8 k + bf16 v, bf16 q/skip/out ----------------
static __device__ __forceinline__ void edge_step(const unsigned int ku, const ushort4 vv,
                                                 const float a,
                                                 const float4 qf, const float4 we4,
                                                 float& ssum, float& ax, float& ay,
                                                 float& az, float& aw)
{
    const f32x2 k01 = __builtin_amdgcn_cvt_pk_f32_fp8((int)ku, false);
    const f32x2 k23 = __builtin_amdgcn_cvt_pk_f32_fp8((int)ku, true);
    float p = qf.x * (k01[0] + a * we4.x) + qf.y * (k01[1] + a * we4.y)
            + qf.z * (k23[0] + a * we4.z) + qf.w * (k23[1] + a * we4.w);
    p += __shfl_xor(p, 1); p += __shfl_xor(p, 2);
    p += __shfl_xor(p, 4); p += __shfl_xor(p, 8);
    const float wgt = __expf(p * 0.125f);
    ssum += wgt;
    ax += wgt * (b2f(vv.x) + a * we4.x);
    ay += wgt * (b2f(vv.y) + a * we4.y);
    az += wgt * (b2f(vv.z) + a * we4.z);
    aw += wgt * (b2f(vv.w) + a * we4.w);
}

__global__ __launch_bounds__(256) void attn_k(const unsigned short* __restrict__ qb,
                                              const unsigned char* __restrict__ kvb,
                                              const float* __restrict__ We,
                                              const int* __restrict__ row_start,
                                              const int2* __restrict__ ekv,
                                              unsigned short* __restrict__ out)
{
    const int wid  = threadIdx.x >> 6;
    const int lane = threadIdx.x & 63;
    const int n = blockIdx.x * 4 + wid;    // grid*4 == N_NODES exactly

    const ushort4 qv = *(const ushort4*)(qb + (size_t)n * 256 + lane * 4);
    float4 qf;
    qf.x = b2f(qv.x); qf.y = b2f(qv.y); qf.z = b2f(qv.z); qf.w = b2f(qv.w);
    const float4 we4 = *(const float4*)(We + lane * 4);
    const int rs = row_start[n], re = row_start[n + 1];
    const int koff = lane << 2;
    const int voff = 256 + (lane << 3);

    float ssum = 0.f;
    float ax = 0.f, ay = 0.f, az = 0.f, aw = 0.f;

    int s = rs;
    for (; s + 4 <= re; s += 4) {
        const int2 p0 = ekv[s],     p1 = ekv[s + 1];
        const int2 p2 = ekv[s + 2], p3 = ekv[s + 3];
        const unsigned char* r0p = kvb + (size_t)p0.x * KVROW;
        const unsigned char* r1p = kvb + (size_t)p1.x * KVROW;
        const unsigned char* r2p = kvb + (size_t)p2.x * KVROW;
        const unsigned char* r3p = kvb + (size_t)p3.x * KVROW;
        const unsigned int k0 = *(const unsigned int*)(r0p + koff);
        const ushort4      v0 = *(const ushort4*)(r0p + voff);
        const unsigned int k1 = *(const unsigned int*)(r1p + koff);
        const ushort4      v1 = *(const ushort4*)(r1p + voff);
        const unsigned int k2 = *(const unsigned int*)(r2p + koff);
        const ushort4      v2 = *(const ushort4*)(r2p + voff);
        const unsigned int k3 = *(const unsigned int*)(r3p + koff);
        const ushort4      v3 = *(const ushort4*)(r3p + voff);
        edge_step(k0, v0, __int_as_float(p0.y), qf, we4, ssum, ax, ay, az, aw);
        edge_step(k1, v1, __int_as_float(p1.y), qf, we4, ssum, ax, ay, az, aw);
        edge_step(k2, v2, __int_as_float(p2.y), qf, we4, ssum, ax, ay, az, aw);
        edge_step(k3, v3, __int_as_float(p3.y), qf, we4, ssum, ax, ay, az, aw);
    }
    for (; s < re; ++s) {
        const int2 p0 = ekv[s];
        const unsigned char* r0p = kvb + (size_t)p0.x * KVROW;
        const unsigned int k0 = *(const unsigned int*)(r0p + koff);
        const ushort4      v0 = *(const ushort4*)(r0p + voff);
        edge_step(k0, v0, __int_as_float(p0.y), qf, we4, ssum, ax, ay, az, aw);
    }
    const float inv = 1.f / (ssum + 1e-16f);
    const ushort4 sk4 = *(const ushort4*)(out + (size_t)n * 256 + lane * 4);
    ushort4 ou;
    ou.x = f2bf(ax * inv + b2f(sk4.x));
    ou.y = f2bf(ay * inv + b2f(sk4.y));
    ou.z = f2bf(az * inv + b2f(sk4.z));
    ou.w = f2bf(aw * inv + b2f(sk4.w));
    *(ushort4*)(out + (size_t)n * 256 + lane * 4) = ou;
}

// ---------------- GraphNorm stats (bf16 input) ----------------
__global__ __launch_bounds__(256) void gn_stats_k(const unsigned short* __restrict__ out,
                                                  float* __restrict__ gstats)
{
    const int c = threadIdx.x;
    float s = 0.f, s2 = 0.f;
    for (int r = blockIdx.x; r < N_NODES; r += gridDim.x) {
        const float vv = b2f(out[(size_t)r * 256 + c]);
        s += vv; s2 += vv * vv;
    }
    atomicAdd(&gstats[c], s);
    atomicAdd(&gstats[256 + c], s2);
}

// ---------------- norm + relu + bf16 transpose: obT[256][SK]; also zeroes xt ----------------
__global__ __launch_bounds__(256) void norm_relu_T(const unsigned short* __restrict__ ob,
                                                   const float* __restrict__ gstats,
                                                   const float* __restrict__ gw,
                                                   const float* __restrict__ gb,
                                                   const float* __restrict__ gms,
                                                   unsigned short* __restrict__ obT,
                                                   float* __restrict__ xt)
{
    __shared__ unsigned short tile[256][72];   // [col][row], 16B-aligned rows (144B)
    __shared__ float smu[256], swi[256], sbd[256];
    const int t = threadIdx.x;
    const int r0 = blockIdx.x * 64;
    {   // zero xt for gram's atomics (gram runs after this kernel in stream order)
        const int zi = blockIdx.x * 256 + t;
        if (zi < 65536) xt[zi] = 0.f;
    }
    {
        const float invN = 1.f / (float)N_NODES;
        const float mean = gstats[t] * invN;
        const float exx  = gstats[256 + t] * invN;
        const float mu   = gms[t] * mean;
        const float var  = exx - 2.f * mu * mean + mu * mu;
        smu[t] = mu;
        swi[t] = gw[t] * rsqrtf(var + 1e-5f);
        sbd[t] = gb[t];
    }
    __syncthreads();
    const int rr = t >> 2;
    const int row = r0 + rr;
#pragma unroll
    for (int it = 0; it < 16; ++it) {
        const int col = it * 16 + (t & 3) * 4;
        ushort4 u;
        if (row < N_NODES) {
            const ushort4 uv = *(const ushort4*)(ob + (size_t)row * 256 + col);
            u.x = f2bf(fmaxf((b2f(uv.x) - smu[col + 0]) * swi[col + 0] + sbd[col + 0], 0.f));
            u.y = f2bf(fmaxf((b2f(uv.y) - smu[col + 1]) * swi[col + 1] + sbd[col + 1], 0.f));
            u.z = f2bf(fmaxf((b2f(uv.z) - smu[col + 2]) * swi[col + 2] + sbd[col + 2], 0.f));
            u.w = f2bf(fmaxf((b2f(uv.w) - smu[col + 3]) * swi[col + 3] + sbd[col + 3], 0.f));
        } else { u.x = u.y = u.z = u.w = 0; }
        tile[col + 0][rr] = u.x;
        tile[col + 1][rr] = u.y;
        tile[col + 2][rr] = u.z;
        tile[col + 3][rr] = u.w;
    }
    __syncthreads();
#pragma unroll
    for (int it = 0; it < 8; ++it) {
        const int c = it * 32 + (t >> 3);
        const int part = t & 7;
        const uint4 x0 = *(const uint4*)&tile[c][part * 8];
        *(uint4*)(obT + (size_t)c * SK + r0 + part * 8) = x0;
    }
}

// ---------------- Gram: xt = P^T P via bf16 MFMA on obT, pipelined chunks ----------------
__global__ __launch_bounds__(256) void gram_k(const unsigned short* __restrict__ obT,
                                              float* __restrict__ xt)
{
    const int bi_l[10] = {0,0,0,0,1,1,1,2,2,3};
    const int bj_l[10] = {0,1,2,3,1,2,3,2,3,3};
    const int bi = bi_l[blockIdx.x], bj = bj_l[blockIdx.x];
    const int r0 = blockIdx.y * 256;         // K chunk (SK/80 = 256)

    __shared__ __align__(16) unsigned short Ai[64 * GPITCH];
    __shared__ __align__(16) unsigned short Aj[64 * GPITCH];
    const int tid = threadIdx.x;
    const int lane = tid & 63;
    const int w = tid >> 6;                  // 4 waves, 2x2
    const int wi = w >> 1, wj = w & 1;
    const int lr = tid >> 2, kseg = (tid & 3) * 32;
    const int fr = lane & 15, fk = (lane >> 4) * 8, lg = lane >> 4;

    f32x4 acc[2][2] = {};

    const unsigned short* pa = obT + (size_t)(bi * 64 + lr) * SK + r0 + kseg;
    const unsigned short* pb = obT + (size_t)(bj * 64 + lr) * SK + r0 + kseg;
    uint4 ai[4], aj[4];
#pragma unroll
    for (int j = 0; j < 4; ++j) { ai[j] = *(const uint4*)(pa + 8 * j); aj[j] = *(const uint4*)(pb + 8 * j); }

#pragma unroll
    for (int itr = 0; itr < 2; ++itr) {
        __syncthreads();
#pragma unroll
        for (int j = 0; j < 4; ++j) {
            *(uint4*)&Ai[lr * GPITCH + kseg + 8 * j] = ai[j];
            *(uint4*)&Aj[lr * GPITCH + kseg + 8 * j] = aj[j];
        }
        __syncthreads();
        if (itr == 0) {
#pragma unroll
            for (int j = 0; j < 4; ++j) {
                ai[j] = *(const uint4*)(pa + 128 + 8 * j);
                aj[j] = *(const uint4*)(pb + 128 + 8 * j);
            }
        }
#pragma unroll
        for (int ks = 0; ks < 4; ++ks) {
            short8 af[2], bf[2];
#pragma unroll
            for (int m = 0; m < 2; ++m)
                af[m] = *(const short8*)&Ai[(wi * 32 + m * 16 + fr) * GPITCH + ks * 32 + fk];
#pragma unroll
            for (int n = 0; n < 2; ++n)
                bf[n] = *(const short8*)&Aj[(wj * 32 + n * 16 + fr) * GPITCH + ks * 32 + fk];
#pragma unroll
            for (int m = 0; m < 2; ++m)
#pragma unroll
                for (int n = 0; n < 2; ++n)
                    acc[m][n] = __builtin_amdgcn_mfma_f32_16x16x32_bf16(af[m], bf[n], acc[m][n], 0, 0, 0);
        }
    }
#pragma unroll
    for (int m = 0; m < 2; ++m)
#pragma unroll
        for (int n = 0; n < 2; ++n)
#pragma unroll
            for (int r = 0; r < 4; ++r)
                atomicAdd(&xt[(size_t)(bi * 64 + wi * 32 + m * 16 + lg * 4 + r) * 256
                              + bj * 64 + wj * 32 + n * 16 + fr], acc[m][n][r]);
}

// ---------------- fused min/max + finalize (single block) ----------------
__global__ __launch_bounds__(1024) void minmax_fin_k(const float* __restrict__ xt,
                                                     float* __restrict__ outp)
{
    const int tid = threadIdx.x;
    float mn = 1e30f, mx = -1e30f;
    for (int i = tid; i < 65536; i += 1024) {
        const int r = i >> 8, c = i & 255;
        if ((r >> 6) <= (c >> 6)) {
            const float v = xt[i];
            mn = fminf(mn, v);
            mx = fmaxf(mx, v);
        }
    }
    for (int off = 1; off < 64; off <<= 1) {
        mn = fminf(mn, __shfl_xor(mn, off));
        mx = fmaxf(mx, __shfl_xor(mx, off));
    }
    __shared__ float smn[16], smx[16];
    __shared__ float fmn, fmx;
    const int w = tid >> 6;
    if ((tid & 63) == 0) { smn[w] = mn; smx[w] = mx; }
    __syncthreads();
    if (tid == 0) {
        for (int i = 1; i < 16; ++i) {
            mn = fminf(mn, smn[i]);
            mx = fmaxf(mx, smx[i]);
        }
        fmn = mn; fmx = mx;
    }
    __syncthreads();
    const float gmn = fmn;
    const float inv = 1.f / (fmx - gmn + 1e-8f);
    for (int i = tid; i < 65536; i += 1024) {
        const int r = i >> 8, c = i & 255;
        const float v = ((r >> 6) <= (c >> 6)) ? xt[i] : xt[c * 256 + r];
        outp[i] = (v - gmn) * inv;
    }
}

// ---------------- launch ----------------
extern "C" void kernel_launch(void* const* d_in, const int* in_sizes, int n_in,
                              void* d_out, int out_size, void* d_ws, size_t ws_size,
                              hipStream_t stream)
{
    (void)in_sizes; (void)n_in; (void)out_size; (void)ws_size;
    const float* x   = (const float*)d_in[0];
    const int*   ei  = (const int*)d_in[1];
    const float* ea  = (const float*)d_in[2];
    const float* Wq  = (const float*)d_in[3];
    const float* bq  = (const float*)d_in[4];
    const float* Wk  = (const float*)d_in[5];
    const float* bk  = (const float*)d_in[6];
    const float* Wv  = (const float*)d_in[7];
    const float* bv  = (const float*)d_in[8];
    const float* We  = (const float*)d_in[9];
    const float* Wsk = (const float*)d_in[10];
    const float* bsk = (const float*)d_in[11];
    const float* gw  = (const float*)d_in[12];
    const float* gb  = (const float*)d_in[13];
    const float* gms = (const float*)d_in[14];
    float* outp = (float*)d_out;

    char* ws = (char*)d_ws;
    size_t off = 0;
    #define WS_ALLOC(nbytes) (ws + off); off = (off + (size_t)(nbytes) + 255) & ~(size_t)255
    unsigned short* xb  = (unsigned short*)WS_ALLOC((size_t)N_NODES * 256 * 2);   // dead after gemm
    unsigned short* wT  = (unsigned short*)WS_ALLOC((size_t)1024 * 256 * 2);      // dead after gemm
    float* bias_all     = (float*)WS_ALLOC(1024 * 4);                             // dead after gemm
    unsigned short* qb  = (unsigned short*)WS_ALLOC((size_t)N_NODES * 256 * 2);   // bf16 q
    unsigned char*  kvb = (unsigned char*)WS_ALLOC((size_t)N_NODES * KVROW);      // [k fp8 | v bf16]
    unsigned short* ob  = (unsigned short*)WS_ALLOC((size_t)N_NODES * 256 * 2);   // bf16 skip->out
    int*   deg          = (int*)WS_ALLOC((size_t)N_NODES * 4);                    // zeroed by prep_k
    int*   cur          = (int*)WS_ALLOC((size_t)N_NODES * 4);                    // zeroed by scan_k
    float* gstats       = (float*)WS_ALLOC(512 * 4);                              // zeroed by fill_csr
    float* xt           = (float*)WS_ALLOC(65536 * 4);                            // zeroed by norm_relu_T
    int* row_start      = (int*)WS_ALLOC((size_t)(N_NODES + 1) * 4);
    #undef WS_ALLOC
    // overlays rooted at xb (disjoint lifetimes):
    //   ekv (2.56 MB) live [fill_csr, attn];  obT (10.49 MB) live [norm_relu_T, gram]
    int2* ekv           = (int2*)xb;
    unsigned short* obT = (unsigned short*)xb;

    const int* srcv = ei;            // edge_index[0]
    const int* dstv = ei + N_EDGES;  // edge_index[1]

    prep_k<<<2500 + 1024 + 79, 256, 0, stream>>>(x, xb, Wq, Wk, Wv, Wsk,
                                                 bq, bk, bv, bsk, wT, bias_all, deg);

    gemm_qkvs<<<dim3(157, 9), 256, 0, stream>>>(xb, wT, bias_all,
                                                qb, kvb, ob, dstv, deg);

    scan_k<<<1, 1024, 0, stream>>>(deg, row_start, cur);
    fill_csr<<<(N_EDGES + 255) / 256, 256, 0, stream>>>(dstv, srcv, ea, row_start,
                                                        cur, ekv, gstats);

    attn_k<<<N_NODES / 4, 256, 0, stream>>>(qb, kvb, We, row_start, ekv, ob);

    gn_stats_k<<<400, 256, 0, stream>>>(ob, gstats);
    norm_relu_T<<<320, 256, 0, stream>>>(ob, gstats, gw, gb, gms, obT, xt);

    gram_k<<<dim3(10, 80), 256, 0, stream>>>(obT, xt);
    minmax_fin_k<<<1, 1024, 0, stream>>>(xt, outp);
}

// Round 18
// 216.950 us; speedup vs baseline: 1.0680x; 1.0680x over previous
//
#include <hip/hip_runtime.h>
#include <math.h>

#define N_NODES 20000
#define N_EDGES 320000
#define SK 20480   // zero-padded K (rows) for transposed gram operand
#define APAD 80    // gemm LDS pitch (elems)
#define GPITCH 144 // gram LDS pitch (elems)
#define KVROW 768  // kv row bytes: [k fp8 256B][v bf16 512B]

typedef short short8 __attribute__((ext_vector_type(8)));
typedef float f32x4 __attribute__((ext_vector_type(4)));
typedef float f32x2 __attribute__((ext_vector_type(2)));

static __device__ __forceinline__ unsigned short f2bf(float f) {
    unsigned int u = __float_as_uint(f);
    u = (u + 0x7FFF + ((u >> 16) & 1)) >> 16;
    return (unsigned short)u;
}
static __device__ __forceinline__ float b2f(unsigned short u) {
    return __uint_as_float((unsigned int)u << 16);
}

// ---------------- fused prep: conv_x (2500) | conv_w LDS-transpose (64) | zero deg (79) ----------------
__global__ __launch_bounds__(256) void prep_k(const float* __restrict__ x,
                                              unsigned short* __restrict__ xb,
                                              const float* __restrict__ Wq,
                                              const float* __restrict__ Wk,
                                              const float* __restrict__ Wv,
                                              const float* __restrict__ Wsk,
                                              const float* __restrict__ bq,
                                              const float* __restrict__ bk,
                                              const float* __restrict__ bv,
                                              const float* __restrict__ bsk,
                                              unsigned short* __restrict__ wT,
                                              float* __restrict__ bias_all,
                                              int* __restrict__ deg)
{
    __shared__ float tw[64][65];       // pitch 65 (odd words) -> conflict-free transpose
    const int b = blockIdx.x;
    const int tid = threadIdx.x;
    if (b < 2500) {
        const size_t base = ((size_t)b * 256 + tid) * 8;
        const float4 f0 = *(const float4*)(x + base);
        const float4 f1 = *(const float4*)(x + base + 4);
        ushort4 u0, u1;
        u0.x = f2bf(f0.x); u0.y = f2bf(f0.y); u0.z = f2bf(f0.z); u0.w = f2bf(f0.w);
        u1.x = f2bf(f1.x); u1.y = f2bf(f1.y); u1.z = f2bf(f1.z); u1.w = f2bf(f1.w);
        *(ushort4*)(xb + base) = u0;
        *(ushort4*)(xb + base + 4) = u1;
    } else if (b < 2564) {
        const int b2 = b - 2500;               // 0..63
        const int wi = b2 >> 4;                // matrix
        const int t2 = b2 & 15;
        const int n0 = (t2 & 3) * 64;          // output-col tile
        const int k0 = (t2 >> 2) * 64;         // k tile
        const float* W = (wi == 0) ? Wq : (wi == 1) ? Wk : (wi == 2) ? Wv : Wsk;
        const int r = tid >> 6, c = tid & 63;
#pragma unroll
        for (int it = 0; it < 16; ++it) {
            const int row = it * 4 + r;
            tw[row][c] = W[(size_t)(k0 + row) * 256 + n0 + c];   // coalesced 256B rows
        }
        __syncthreads();
#pragma unroll
        for (int it = 0; it < 16; ++it) {
            const int n = it * 4 + r;
            wT[(size_t)(wi * 256 + n0 + n) * 256 + k0 + c] = f2bf(tw[c][n]);
        }
        if (k0 == 0 && tid < 64) {
            const float* bv_ = (wi == 0) ? bq : (wi == 1) ? bk : (wi == 2) ? bv : bsk;
            bias_all[wi * 256 + n0 + tid] = bv_[n0 + tid];
        }
    } else {
        const int i = (b - 2564) * 256 + tid;
        if (i < N_NODES) deg[i] = 0;
    }
}

// ---------------- fused QKVS GEMM (pipelined LDS) + count_deg plane ----------------
// grid (157, 9): by 0..7 gemm planes; by==8 count_deg
__global__ __launch_bounds__(256, 4) void gemm_qkvs(const unsigned short* __restrict__ xb,
                                                    const unsigned short* __restrict__ wT,
                                                    const float* __restrict__ bias_all,
                                                    unsigned short* __restrict__ qb,
                                                    unsigned char* __restrict__ kvb,
                                                    unsigned short* __restrict__ ob,
                                                    const int* __restrict__ dst,
                                                    int* __restrict__ deg)
{
    const int tid  = threadIdx.x;
    const int by   = blockIdx.y;
    if (by == 8) {                     // degree count (deg zeroed by prep_k)
        for (int e = blockIdx.x * 256 + tid; e < N_EDGES; e += 157 * 256)
            atomicAdd(&deg[dst[e]], 1);
        return;
    }

    __shared__ __align__(16) unsigned short As[(128 + 128) * APAD];
    unsigned short* Bs = As + 128 * APAD;
    float* stage = (float*)As;                                      // reused after K-loop

    const int lane = tid & 63;
    const int w    = tid >> 6;         // 0..3
    const int wm = w >> 1, wn = w & 1; // wave grid 2x2
    const int row0 = blockIdx.x * 128;
    const int wsel = by >> 1;          // 0=q 1=k 2=v 3=skip
    const int ar = tid >> 1, ak = (tid & 1) * 32;
    const int fr = lane & 15, fk = (lane >> 4) * 8, lg = lane >> 4;

    int gr = row0 + ar; gr = gr < N_NODES ? gr : N_NODES - 1;
    const unsigned short* ab = xb + (size_t)gr * 256 + ak;
    const unsigned short* bb = wT + (size_t)(by * 128 + ar) * 256 + ak;

    f32x4 acc[4][4] = {};
    uint4 a0, a1, a2, a3, b0, b1, b2, b3;

    a0 = *(const uint4*)ab;        a1 = *(const uint4*)(ab + 8);
    a2 = *(const uint4*)(ab + 16); a3 = *(const uint4*)(ab + 24);
    b0 = *(const uint4*)bb;        b1 = *(const uint4*)(bb + 8);
    b2 = *(const uint4*)(bb + 16); b3 = *(const uint4*)(bb + 24);

#pragma unroll
    for (int it = 0; it < 4; ++it) {
        __syncthreads();
        unsigned short* asp = &As[ar * APAD + ak];
        *(uint4*)asp        = a0;
        *(uint4*)(asp + 8)  = a1;
        *(uint4*)(asp + 16) = a2;
        *(uint4*)(asp + 24) = a3;
        unsigned short* bsp = &Bs[ar * APAD + ak];
        *(uint4*)bsp        = b0;
        *(uint4*)(bsp + 8)  = b1;
        *(uint4*)(bsp + 16) = b2;
        *(uint4*)(bsp + 24) = b3;
        __syncthreads();
        if (it < 3) {
            const unsigned short* ap = ab + (it + 1) * 64;
            const unsigned short* bp = bb + (it + 1) * 64;
            a0 = *(const uint4*)ap;        a1 = *(const uint4*)(ap + 8);
            a2 = *(const uint4*)(ap + 16); a3 = *(const uint4*)(ap + 24);
            b0 = *(const uint4*)bp;        b1 = *(const uint4*)(bp + 8);
            b2 = *(const uint4*)(bp + 16); b3 = *(const uint4*)(bp + 24);
        }
#pragma unroll
        for (int ks = 0; ks < 2; ++ks) {
            short8 af[4], bf[4];
#pragma unroll
            for (int m = 0; m < 4; ++m)
                af[m] = *(const short8*)&As[(wm * 64 + m * 16 + fr) * APAD + ks * 32 + fk];
#pragma unroll
            for (int n = 0; n < 4; ++n)
                bf[n] = *(const short8*)&Bs[(wn * 64 + n * 16 + fr) * APAD + ks * 32 + fk];
#pragma unroll
            for (int m = 0; m < 4; ++m)
#pragma unroll
                for (int n = 0; n < 4; ++n)
                    acc[m][n] = __builtin_amdgcn_mfma_f32_16x16x32_bf16(af[m], bf[n], acc[m][n], 0, 0, 0);
        }
    }
    __syncthreads();                   // all frag reads done; LDS reusable

    float badd[4];
#pragma unroll
    for (int n = 0; n < 4; ++n) badd[n] = bias_all[by * 128 + wn * 64 + n * 16 + fr];

    float* st = stage + w * 1024;      // 4 KB wave-private staging
    const int chalf = by & 1;
#pragma unroll
    for (int m = 0; m < 4; ++m) {
#pragma unroll
        for (int n = 0; n < 4; ++n)
#pragma unroll
            for (int r = 0; r < 4; ++r)
                st[(lg * 4 + r) * 64 + n * 16 + fr] = acc[m][n][r] + badd[n];
#pragma unroll
        for (int it = 0; it < 4; ++it) {
            const int lrow = it * 4 + lg;
            const f32x4 c4 = *(const f32x4*)&st[lrow * 64 + fr * 4];
            const int grow = row0 + wm * 64 + m * 16 + lrow;
            if (grow < N_NODES) {
                const int colin = chalf * 128 + wn * 64 + fr * 4;
                if (wsel == 1) {
                    int pk = __builtin_amdgcn_cvt_pk_fp8_f32(c4[0], c4[1], 0, false);
                    pk = __builtin_amdgcn_cvt_pk_fp8_f32(c4[2], c4[3], pk, true);
                    *(unsigned int*)(kvb + (size_t)grow * KVROW + colin) = (unsigned int)pk;
                } else {
                    ushort4 u;
                    u.x = f2bf(c4[0]); u.y = f2bf(c4[1]); u.z = f2bf(c4[2]); u.w = f2bf(c4[3]);
                    if (wsel == 3) {
                        *(ushort4*)(ob + (size_t)grow * 256 + colin) = u;
                    } else if (wsel == 0) {
                        *(ushort4*)(qb + (size_t)grow * 256 + colin) = u;
                    } else {
                        *(ushort4*)(kvb + (size_t)grow * KVROW + 256 + colin * 2) = u;
                    }
                }
            }
        }
    }
}

// ---------------- CSR scan (coalesced staging; also zeroes cursor) ----------------
__global__ __launch_bounds__(1024) void scan_k(const int* __restrict__ deg,
                                               int* __restrict__ row_start,
                                               int* __restrict__ cursor)
{
    __shared__ int sdeg[20480];
    const int tid = threadIdx.x;
    const int lane = tid & 63, wid = tid >> 6;
    const int CH = 20;
#pragma unroll
    for (int i = 0; i < 20; ++i) {
        const int idx = i * 1024 + tid;
        sdeg[idx] = (idx < N_NODES) ? deg[idx] : 0;
    }
    __syncthreads();
    const int base = tid * CH;
    int local[CH];
    int s = 0;
#pragma unroll
    for (int i = 0; i < CH; ++i) {
        local[i] = s;
        s += sdeg[base + i];
    }
    int v = s;
#pragma unroll
    for (int off = 1; off < 64; off <<= 1) {
        const int t = __shfl_up(v, off);
        if (lane >= off) v += t;
    }
    __shared__ int wsum[16];
    if (lane == 63) wsum[wid] = v;
    __syncthreads();
    if (tid == 0) {
        int r = 0;
        for (int i = 0; i < 16; ++i) { const int t = wsum[i]; wsum[i] = r; r += t; }
    }
    __syncthreads();
    const int excl = v - s + wsum[wid];
#pragma unroll
    for (int i = 0; i < CH; ++i) {
        const int idx = base + i;
        if (idx < N_NODES) {
            row_start[idx] = excl + local[i];
            cursor[idx] = 0;
        }
    }
    if (tid == 1023) row_start[N_NODES] = excl + s;
}

__global__ void fill_csr(const int* __restrict__ dst, const int* __restrict__ src,
                         const float* __restrict__ ea,
                         const int* __restrict__ row_start,
                         int* __restrict__ cursor, int2* __restrict__ ekv,
                         float* __restrict__ gstats)
{
    const int g = blockIdx.x * 256 + threadIdx.x;
    if (g < 512) gstats[g] = 0.f;
    const int e = g;
    if (e < N_EDGES) {
        const int d = dst[e];
        const int p = atomicAdd(&cursor[d], 1);
        int2 pk;
        pk.x = src[e];
        pk.y = __float_as_int(ea[e]);
        ekv[row_start[d] + p] = pk;
    }
}

// ---------------- attention: single pass, fp8 k + bf16 v, bf16 q/skip/out ----------------
static __device__ __forceinline__ void edge_step(const unsigned int ku, const ushort4 vv,
                                                 const float a,
                                                 const float4 qf, const float4 we4,
                                                 float& ssum, float& ax, float& ay,
                                                 float& az, float& aw)
{
    const f32x2 k01 = __builtin_amdgcn_cvt_pk_f32_fp8((int)ku, false);
    const f32x2 k23 = __builtin_amdgcn_cvt_pk_f32_fp8((int)ku, true);
    float p = qf.x * (k01[0] + a * we4.x) + qf.y * (k01[1] + a * we4.y)
            + qf.z * (k23[0] + a * we4.z) + qf.w * (k23[1] + a * we4.w);
    p += __shfl_xor(p, 1); p += __shfl_xor(p, 2);
    p += __shfl_xor(p, 4); p += __shfl_xor(p, 8);
    const float wgt = __expf(p * 0.125f);
    ssum += wgt;
    ax += wgt * (b2f(vv.x) + a * we4.x);
    ay += wgt * (b2f(vv.y) + a * we4.y);
    az += wgt * (b2f(vv.z) + a * we4.z);
    aw += wgt * (b2f(vv.w) + a * we4.w);
}

__global__ __launch_bounds__(256) void attn_k(const unsigned short* __restrict__ qb,
                                              const unsigned char* __restrict__ kvb,
                                              const float* __restrict__ We,
                                              const int* __restrict__ row_start,
                                              const int2* __restrict__ ekv,
                                              unsigned short* __restrict__ out)
{
    const int wid  = threadIdx.x >> 6;
    const int lane = threadIdx.x & 63;
    const int n = blockIdx.x * 4 + wid;

    const ushort4 qv = *(const ushort4*)(qb + (size_t)n * 256 + lane * 4);
    float4 qf;
    qf.x = b2f(qv.x); qf.y = b2f(qv.y); qf.z = b2f(qv.z); qf.w = b2f(qv.w);
    const float4 we4 = *(const float4*)(We + lane * 4);
    const int rs = row_start[n], re = row_start[n + 1];
    const int koff = lane << 2;
    const int voff = 256 + (lane << 3);

    float ssum = 0.f;
    float ax = 0.f, ay = 0.f, az = 0.f, aw = 0.f;

    int s = rs;
    for (; s + 4 <= re; s += 4) {
        const int2 p0 = ekv[s],     p1 = ekv[s + 1];
        const int2 p2 = ekv[s + 2], p3 = ekv[s + 3];
        const unsigned char* r0p = kvb + (size_t)p0.x * KVROW;
        const unsigned char* r1p = kvb + (size_t)p1.x * KVROW;
        const unsigned char* r2p = kvb + (size_t)p2.x * KVROW;
        const unsigned char* r3p = kvb + (size_t)p3.x * KVROW;
        const unsigned int k0 = *(const unsigned int*)(r0p + koff);
        const ushort4      v0 = *(const ushort4*)(r0p + voff);
        const unsigned int k1 = *(const unsigned int*)(r1p + koff);
        const ushort4      v1 = *(const ushort4*)(r1p + voff);
        const unsigned int k2 = *(const unsigned int*)(r2p + koff);
        const ushort4      v2 = *(const ushort4*)(r2p + voff);
        const unsigned int k3 = *(const unsigned int*)(r3p + koff);
        const ushort4      v3 = *(const ushort4*)(r3p + voff);
        edge_step(k0, v0, __int_as_float(p0.y), qf, we4, ssum, ax, ay, az, aw);
        edge_step(k1, v1, __int_as_float(p1.y), qf, we4, ssum, ax, ay, az, aw);
        edge_step(k2, v2, __int_as_float(p2.y), qf, we4, ssum, ax, ay, az, aw);
        edge_step(k3, v3, __int_as_float(p3.y), qf, we4, ssum, ax, ay, az, aw);
    }
    for (; s < re; ++s) {
        const int2 p0 = ekv[s];
        const unsigned char* r0p = kvb + (size_t)p0.x * KVROW;
        const unsigned int k0 = *(const unsigned int*)(r0p + koff);
        const ushort4      v0 = *(const ushort4*)(r0p + voff);
        edge_step(k0, v0, __int_as_float(p0.y), qf, we4, ssum, ax, ay, az, aw);
    }
    const float inv = 1.f / (ssum + 1e-16f);
    const ushort4 sk4 = *(const ushort4*)(out + (size_t)n * 256 + lane * 4);
    ushort4 ou;
    ou.x = f2bf(ax * inv + b2f(sk4.x));
    ou.y = f2bf(ay * inv + b2f(sk4.y));
    ou.z = f2bf(az * inv + b2f(sk4.z));
    ou.w = f2bf(aw * inv + b2f(sk4.w));
    *(ushort4*)(out + (size_t)n * 256 + lane * 4) = ou;
}

// ---------------- GraphNorm stats (bf16 input) ----------------
__global__ __launch_bounds__(256) void gn_stats_k(const unsigned short* __restrict__ out,
                                                  float* __restrict__ gstats)
{
    const int c = threadIdx.x;
    float s = 0.f, s2 = 0.f;
    for (int r = blockIdx.x; r < N_NODES; r += gridDim.x) {
        const float vv = b2f(out[(size_t)r * 256 + c]);
        s += vv; s2 += vv * vv;
    }
    atomicAdd(&gstats[c], s);
    atomicAdd(&gstats[256 + c], s2);
}

// ---------------- norm + relu + bf16 transpose: obT[256][SK]; also zeroes xt ----------------
__global__ __launch_bounds__(256) void norm_relu_T(const unsigned short* __restrict__ ob,
                                                   const float* __restrict__ gstats,
                                                   const float* __restrict__ gw,
                                                   const float* __restrict__ gb,
                                                   const float* __restrict__ gms,
                                                   unsigned short* __restrict__ obT,
                                                   float* __restrict__ xt)
{
    __shared__ unsigned short tile[256][72];
    __shared__ float smu[256], swi[256], sbd[256];
    const int t = threadIdx.x;
    const int r0 = blockIdx.x * 64;
    {
        const int zi = blockIdx.x * 256 + t;
        if (zi < 65536) xt[zi] = 0.f;
    }
    {
        const float invN = 1.f / (float)N_NODES;
        const float mean = gstats[t] * invN;
        const float exx  = gstats[256 + t] * invN;
        const float mu   = gms[t] * mean;
        const float var  = exx - 2.f * mu * mean + mu * mu;
        smu[t] = mu;
        swi[t] = gw[t] * rsqrtf(var + 1e-5f);
        sbd[t] = gb[t];
    }
    __syncthreads();
    const int rr = t >> 2;
    const int row = r0 + rr;
#pragma unroll
    for (int it = 0; it < 16; ++it) {
        const int col = it * 16 + (t & 3) * 4;
        ushort4 u;
        if (row < N_NODES) {
            const ushort4 uv = *(const ushort4*)(ob + (size_t)row * 256 + col);
            u.x = f2bf(fmaxf((b2f(uv.x) - smu[col + 0]) * swi[col + 0] + sbd[col + 0], 0.f));
            u.y = f2bf(fmaxf((b2f(uv.y) - smu[col + 1]) * swi[col + 1] + sbd[col + 1], 0.f));
            u.z = f2bf(fmaxf((b2f(uv.z) - smu[col + 2]) * swi[col + 2] + sbd[col + 2], 0.f));
            u.w = f2bf(fmaxf((b2f(uv.w) - smu[col + 3]) * swi[col + 3] + sbd[col + 3], 0.f));
        } else { u.x = u.y = u.z = u.w = 0; }
        tile[col + 0][rr] = u.x;
        tile[col + 1][rr] = u.y;
        tile[col + 2][rr] = u.z;
        tile[col + 3][rr] = u.w;
    }
    __syncthreads();
#pragma unroll
    for (int it = 0; it < 8; ++it) {
        const int c = it * 32 + (t >> 3);
        const int part = t & 7;
        const uint4 x0 = *(const uint4*)&tile[c][part * 8];
        *(uint4*)(obT + (size_t)c * SK + r0 + part * 8) = x0;
    }
}

// ---------------- Gram: xt = P^T P via bf16 MFMA on obT, pipelined chunks ----------------
__global__ __launch_bounds__(256) void gram_k(const unsigned short* __restrict__ obT,
                                              float* __restrict__ xt)
{
    const int bi_l[10] = {0,0,0,0,1,1,1,2,2,3};
    const int bj_l[10] = {0,1,2,3,1,2,3,2,3,3};
    const int bi = bi_l[blockIdx.x], bj = bj_l[blockIdx.x];
    const int r0 = blockIdx.y * 256;

    __shared__ __align__(16) unsigned short Ai[64 * GPITCH];
    __shared__ __align__(16) unsigned short Aj[64 * GPITCH];
    const int tid = threadIdx.x;
    const int lane = tid & 63;
    const int w = tid >> 6;
    const int wi = w >> 1, wj = w & 1;
    const int lr = tid >> 2, kseg = (tid & 3) * 32;
    const int fr = lane & 15, fk = (lane >> 4) * 8, lg = lane >> 4;

    f32x4 acc[2][2] = {};

    const unsigned short* pa = obT + (size_t)(bi * 64 + lr) * SK + r0 + kseg;
    const unsigned short* pb = obT + (size_t)(bj * 64 + lr) * SK + r0 + kseg;
    uint4 ai[4], aj[4];
#pragma unroll
    for (int j = 0; j < 4; ++j) { ai[j] = *(const uint4*)(pa + 8 * j); aj[j] = *(const uint4*)(pb + 8 * j); }

#pragma unroll
    for (int itr = 0; itr < 2; ++itr) {
        __syncthreads();
#pragma unroll
        for (int j = 0; j < 4; ++j) {
            *(uint4*)&Ai[lr * GPITCH + kseg + 8 * j] = ai[j];
            *(uint4*)&Aj[lr * GPITCH + kseg + 8 * j] = aj[j];
        }
        __syncthreads();
        if (itr == 0) {
#pragma unroll
            for (int j = 0; j < 4; ++j) {
                ai[j] = *(const uint4*)(pa + 128 + 8 * j);
                aj[j] = *(const uint4*)(pb + 128 + 8 * j);
            }
        }
#pragma unroll
        for (int ks = 0; ks < 4; ++ks) {
            short8 af[2], bf[2];
#pragma unroll
            for (int m = 0; m < 2; ++m)
                af[m] = *(const short8*)&Ai[(wi * 32 + m * 16 + fr) * GPITCH + ks * 32 + fk];
#pragma unroll
            for (int n = 0; n < 2; ++n)
                bf[n] = *(const short8*)&Aj[(wj * 32 + n * 16 + fr) * GPITCH + ks * 32 + fk];
#pragma unroll
            for (int m = 0; m < 2; ++m)
#pragma unroll
                for (int n = 0; n < 2; ++n)
                    acc[m][n] = __builtin_amdgcn_mfma_f32_16x16x32_bf16(af[m], bf[n], acc[m][n], 0, 0, 0);
        }
    }
#pragma unroll
    for (int m = 0; m < 2; ++m)
#pragma unroll
        for (int n = 0; n < 2; ++n)
#pragma unroll
            for (int r = 0; r < 4; ++r)
                atomicAdd(&xt[(size_t)(bi * 64 + wi * 32 + m * 16 + lg * 4 + r) * 256
                              + bj * 64 + wj * 32 + n * 16 + fr], acc[m][n][r]);
}

// ---------------- fused min/max + finalize (single block) ----------------
__global__ __launch_bounds__(1024) void minmax_fin_k(const float* __restrict__ xt,
                                                     float* __restrict__ outp)
{
    const int tid = threadIdx.x;
    float mn = 1e30f, mx = -1e30f;
    for (int i = tid; i < 65536; i += 1024) {
        const int r = i >> 8, c = i & 255;
        if ((r >> 6) <= (c >> 6)) {
            const float v = xt[i];
            mn = fminf(mn, v);
            mx = fmaxf(mx, v);
        }
    }
    for (int off = 1; off < 64; off <<= 1) {
        mn = fminf(mn, __shfl_xor(mn, off));
        mx = fmaxf(mx, __shfl_xor(mx, off));
    }
    __shared__ float smn[16], smx[16];
    __shared__ float fmn, fmx;
    const int w = tid >> 6;
    if ((tid & 63) == 0) { smn[w] = mn; smx[w] = mx; }
    __syncthreads();
    if (tid == 0) {
        for (int i = 1; i < 16; ++i) {
            mn = fminf(mn, smn[i]);
            mx = fmaxf(mx, smx[i]);
        }
        fmn = mn; fmx = mx;
    }
    __syncthreads();
    const float gmn = fmn;
    const float inv = 1.f / (fmx - gmn + 1e-8f);
    for (int i = tid; i < 65536; i += 1024) {
        const int r = i >> 8, c = i & 255;
        const float v = ((r >> 6) <= (c >> 6)) ? xt[i] : xt[c * 256 + r];
        outp[i] = (v - gmn) * inv;
    }
}

// ---------------- launch ----------------
extern "C" void kernel_launch(void* const* d_in, const int* in_sizes, int n_in,
                              void* d_out, int out_size, void* d_ws, size_t ws_size,
                              hipStream_t stream)
{
    (void)in_sizes; (void)n_in; (void)out_size; (void)ws_size;
    const float* x   = (const float*)d_in[0];
    const int*   ei  = (const int*)d_in[1];
    const float* ea  = (const float*)d_in[2];
    const float* Wq  = (const float*)d_in[3];
    const float* bq  = (const float*)d_in[4];
    const float* Wk  = (const float*)d_in[5];
    const float* bk  = (const float*)d_in[6];
    const float* Wv  = (const float*)d_in[7];
    const float* bv  = (const float*)d_in[8];
    const float* We  = (const float*)d_in[9];
    const float* Wsk = (const float*)d_in[10];
    const float* bsk = (const float*)d_in[11];
    const float* gw  = (const float*)d_in[12];
    const float* gb  = (const float*)d_in[13];
    const float* gms = (const float*)d_in[14];
    float* outp = (float*)d_out;

    char* ws = (char*)d_ws;
    size_t off = 0;
    #define WS_ALLOC(nbytes) (ws + off); off = (off + (size_t)(nbytes) + 255) & ~(size_t)255
    unsigned short* xb  = (unsigned short*)WS_ALLOC((size_t)N_NODES * 256 * 2);   // dead after gemm
    unsigned short* wT  = (unsigned short*)WS_ALLOC((size_t)1024 * 256 * 2);      // dead after gemm
    float* bias_all     = (float*)WS_ALLOC(1024 * 4);                             // dead after gemm
    unsigned short* qb  = (unsigned short*)WS_ALLOC((size_t)N_NODES * 256 * 2);   // bf16 q
    unsigned char*  kvb = (unsigned char*)WS_ALLOC((size_t)N_NODES * KVROW);      // [k fp8 | v bf16]
    unsigned short* ob  = (unsigned short*)WS_ALLOC((size_t)N_NODES * 256 * 2);   // bf16 skip->out
    int*   deg          = (int*)WS_ALLOC((size_t)N_NODES * 4);                    // zeroed by prep_k
    int*   cur          = (int*)WS_ALLOC((size_t)N_NODES * 4);                    // zeroed by scan_k
    float* gstats       = (float*)WS_ALLOC(512 * 4);                              // zeroed by fill_csr
    float* xt           = (float*)WS_ALLOC(65536 * 4);                            // zeroed by norm_relu_T
    int* row_start      = (int*)WS_ALLOC((size_t)(N_NODES + 1) * 4);
    #undef WS_ALLOC
    // overlays rooted at xb (disjoint lifetimes)
    int2* ekv           = (int2*)xb;
    unsigned short* obT = (unsigned short*)xb;

    const int* srcv = ei;            // edge_index[0]
    const int* dstv = ei + N_EDGES;  // edge_index[1]

    prep_k<<<2500 + 64 + 79, 256, 0, stream>>>(x, xb, Wq, Wk, Wv, Wsk,
                                               bq, bk, bv, bsk, wT, bias_all, deg);

    gemm_qkvs<<<dim3(157, 9), 256, 0, stream>>>(xb, wT, bias_all,
                                                qb, kvb, ob, dstv, deg);

    scan_k<<<1, 1024, 0, stream>>>(deg, row_start, cur);
    fill_csr<<<(N_EDGES + 255) / 256, 256, 0, stream>>>(dstv, srcv, ea, row_start,
                                                        cur, ekv, gstats);

    attn_k<<<N_NODES / 4, 256, 0, stream>>>(qb, kvb, We, row_start, ekv, ob);

    gn_stats_k<<<400, 256, 0, stream>>>(ob, gstats);
    norm_relu_T<<<320, 256, 0, stream>>>(ob, gstats, gw, gb, gms, obT, xt);

    gram_k<<<dim3(10, 80), 256, 0, stream>>>(obT, xt);
    minmax_fin_k<<<1, 1024, 0, stream>>>(xt, outp);
}

// Round 19
// 209.518 us; speedup vs baseline: 1.1059x; 1.0355x over previous
//
#include <hip/hip_runtime.h>
#include <math.h>

#define N_NODES 20000
#define N_EDGES 320000
#define SK 20480   // zero-padded K (rows) for transposed gram operand
#define APAD 80    // gemm LDS pitch (elems)
#define GPITCH 144 // gram LDS pitch (elems)
#define KVROW 512  // kv row bytes: 64 chunks x [k fp8 4B | v fp8 4B]

typedef short short8 __attribute__((ext_vector_type(8)));
typedef float f32x4 __attribute__((ext_vector_type(4)));
typedef float f32x2 __attribute__((ext_vector_type(2)));

static __device__ __forceinline__ unsigned short f2bf(float f) {
    unsigned int u = __float_as_uint(f);
    u = (u + 0x7FFF + ((u >> 16) & 1)) >> 16;
    return (unsigned short)u;
}
static __device__ __forceinline__ float b2f(unsigned short u) {
    return __uint_as_float((unsigned int)u << 16);
}

// ---------------- fused prep: conv_x (2500) | conv_w LDS-transpose (64) | zero deg (79) ----------------
__global__ __launch_bounds__(256) void prep_k(const float* __restrict__ x,
                                              unsigned short* __restrict__ xb,
                                              const float* __restrict__ Wq,
                                              const float* __restrict__ Wk,
                                              const float* __restrict__ Wv,
                                              const float* __restrict__ Wsk,
                                              const float* __restrict__ bq,
                                              const float* __restrict__ bk,
                                              const float* __restrict__ bv,
                                              const float* __restrict__ bsk,
                                              unsigned short* __restrict__ wT,
                                              float* __restrict__ bias_all,
                                              int* __restrict__ deg)
{
    __shared__ float tw[64][65];       // pitch 65 -> conflict-free transpose
    const int b = blockIdx.x;
    const int tid = threadIdx.x;
    if (b < 2500) {
        const size_t base = ((size_t)b * 256 + tid) * 8;
        const float4 f0 = *(const float4*)(x + base);
        const float4 f1 = *(const float4*)(x + base + 4);
        ushort4 u0, u1;
        u0.x = f2bf(f0.x); u0.y = f2bf(f0.y); u0.z = f2bf(f0.z); u0.w = f2bf(f0.w);
        u1.x = f2bf(f1.x); u1.y = f2bf(f1.y); u1.z = f2bf(f1.z); u1.w = f2bf(f1.w);
        *(ushort4*)(xb + base) = u0;
        *(ushort4*)(xb + base + 4) = u1;
    } else if (b < 2564) {
        const int b2 = b - 2500;               // 0..63
        const int wi = b2 >> 4;
        const int t2 = b2 & 15;
        const int n0 = (t2 & 3) * 64;
        const int k0 = (t2 >> 2) * 64;
        const float* W = (wi == 0) ? Wq : (wi == 1) ? Wk : (wi == 2) ? Wv : Wsk;
        const int r = tid >> 6, c = tid & 63;
#pragma unroll
        for (int it = 0; it < 16; ++it) {
            const int row = it * 4 + r;
            tw[row][c] = W[(size_t)(k0 + row) * 256 + n0 + c];
        }
        __syncthreads();
#pragma unroll
        for (int it = 0; it < 16; ++it) {
            const int n = it * 4 + r;
            wT[(size_t)(wi * 256 + n0 + n) * 256 + k0 + c] = f2bf(tw[c][n]);
        }
        if (k0 == 0 && tid < 64) {
            const float* bv_ = (wi == 0) ? bq : (wi == 1) ? bk : (wi == 2) ? bv : bsk;
            bias_all[wi * 256 + n0 + tid] = bv_[n0 + tid];
        }
    } else {
        const int i = (b - 2564) * 256 + tid;
        if (i < N_NODES) deg[i] = 0;
    }
}

// ---------------- fused QKVS GEMM (pipelined LDS) + count_deg plane ----------------
__global__ __launch_bounds__(256, 4) void gemm_qkvs(const unsigned short* __restrict__ xb,
                                                    const unsigned short* __restrict__ wT,
                                                    const float* __restrict__ bias_all,
                                                    unsigned short* __restrict__ qb,
                                                    unsigned char* __restrict__ kvb,
                                                    unsigned short* __restrict__ ob,
                                                    const int* __restrict__ dst,
                                                    int* __restrict__ deg)
{
    const int tid  = threadIdx.x;
    const int by   = blockIdx.y;
    if (by == 8) {                     // degree count (deg zeroed by prep_k)
        for (int e = blockIdx.x * 256 + tid; e < N_EDGES; e += 157 * 256)
            atomicAdd(&deg[dst[e]], 1);
        return;
    }

    __shared__ __align__(16) unsigned short As[(128 + 128) * APAD];
    unsigned short* Bs = As + 128 * APAD;
    float* stage = (float*)As;

    const int lane = tid & 63;
    const int w    = tid >> 6;
    const int wm = w >> 1, wn = w & 1;
    const int row0 = blockIdx.x * 128;
    const int wsel = by >> 1;          // 0=q 1=k 2=v 3=skip
    const int ar = tid >> 1, ak = (tid & 1) * 32;
    const int fr = lane & 15, fk = (lane >> 4) * 8, lg = lane >> 4;

    int gr = row0 + ar; gr = gr < N_NODES ? gr : N_NODES - 1;
    const unsigned short* ab = xb + (size_t)gr * 256 + ak;
    const unsigned short* bb = wT + (size_t)(by * 128 + ar) * 256 + ak;

    f32x4 acc[4][4] = {};
    uint4 a0, a1, a2, a3, b0, b1, b2, b3;

    a0 = *(const uint4*)ab;        a1 = *(const uint4*)(ab + 8);
    a2 = *(const uint4*)(ab + 16); a3 = *(const uint4*)(ab + 24);
    b0 = *(const uint4*)bb;        b1 = *(const uint4*)(bb + 8);
    b2 = *(const uint4*)(bb + 16); b3 = *(const uint4*)(bb + 24);

#pragma unroll
    for (int it = 0; it < 4; ++it) {
        __syncthreads();
        unsigned short* asp = &As[ar * APAD + ak];
        *(uint4*)asp        = a0;
        *(uint4*)(asp + 8)  = a1;
        *(uint4*)(asp + 16) = a2;
        *(uint4*)(asp + 24) = a3;
        unsigned short* bsp = &Bs[ar * APAD + ak];
        *(uint4*)bsp        = b0;
        *(uint4*)(bsp + 8)  = b1;
        *(uint4*)(bsp + 16) = b2;
        *(uint4*)(bsp + 24) = b3;
        __syncthreads();
        if (it < 3) {
            const unsigned short* ap = ab + (it + 1) * 64;
            const unsigned short* bp = bb + (it + 1) * 64;
            a0 = *(const uint4*)ap;        a1 = *(const uint4*)(ap + 8);
            a2 = *(const uint4*)(ap + 16); a3 = *(const uint4*)(ap + 24);
            b0 = *(const uint4*)bp;        b1 = *(const uint4*)(bp + 8);
            b2 = *(const uint4*)(bp + 16); b3 = *(const uint4*)(bp + 24);
        }
#pragma unroll
        for (int ks = 0; ks < 2; ++ks) {
            short8 af[4], bf[4];
#pragma unroll
            for (int m = 0; m < 4; ++m)
                af[m] = *(const short8*)&As[(wm * 64 + m * 16 + fr) * APAD + ks * 32 + fk];
#pragma unroll
            for (int n = 0; n < 4; ++n)
                bf[n] = *(const short8*)&Bs[(wn * 64 + n * 16 + fr) * APAD + ks * 32 + fk];
#pragma unroll
            for (int m = 0; m < 4; ++m)
#pragma unroll
                for (int n = 0; n < 4; ++n)
                    acc[m][n] = __builtin_amdgcn_mfma_f32_16x16x32_bf16(af[m], bf[n], acc[m][n], 0, 0, 0);
        }
    }
    __syncthreads();

    float badd[4];
#pragma unroll
    for (int n = 0; n < 4; ++n) badd[n] = bias_all[by * 128 + wn * 64 + n * 16 + fr];

    float* st = stage + w * 1024;
    const int chalf = by & 1;
#pragma unroll
    for (int m = 0; m < 4; ++m) {
#pragma unroll
        for (int n = 0; n < 4; ++n)
#pragma unroll
            for (int r = 0; r < 4; ++r)
                st[(lg * 4 + r) * 64 + n * 16 + fr] = acc[m][n][r] + badd[n];
#pragma unroll
        for (int it = 0; it < 4; ++it) {
            const int lrow = it * 4 + lg;
            const f32x4 c4 = *(const f32x4*)&st[lrow * 64 + fr * 4];
            const int grow = row0 + wm * 64 + m * 16 + lrow;
            if (grow < N_NODES) {
                const int colin = chalf * 128 + wn * 64 + fr * 4;
                if (wsel == 1 || wsel == 2) {
                    // k/v -> fp8 e4m3 packed; chunk c: [k 4B | v 4B]
                    int pk = __builtin_amdgcn_cvt_pk_fp8_f32(c4[0], c4[1], 0, false);
                    pk = __builtin_amdgcn_cvt_pk_fp8_f32(c4[2], c4[3], pk, true);
                    const int c = chalf * 32 + wn * 16 + fr;
                    *(unsigned int*)(kvb + (size_t)grow * KVROW + c * 8 + (wsel == 1 ? 0 : 4))
                        = (unsigned int)pk;
                } else {
                    ushort4 u;
                    u.x = f2bf(c4[0]); u.y = f2bf(c4[1]); u.z = f2bf(c4[2]); u.w = f2bf(c4[3]);
                    if (wsel == 3) *(ushort4*)(ob + (size_t)grow * 256 + colin) = u;
                    else           *(ushort4*)(qb + (size_t)grow * 256 + colin) = u;
                }
            }
        }
    }
}

// ---------------- CSR scan (coalesced staging; also zeroes cursor) ----------------
__global__ __launch_bounds__(1024) void scan_k(const int* __restrict__ deg,
                                               int* __restrict__ row_start,
                                               int* __restrict__ cursor)
{
    __shared__ int sdeg[20480];
    const int tid = threadIdx.x;
    const int lane = tid & 63, wid = tid >> 6;
    const int CH = 20;
#pragma unroll
    for (int i = 0; i < 20; ++i) {
        const int idx = i * 1024 + tid;
        sdeg[idx] = (idx < N_NODES) ? deg[idx] : 0;
    }
    __syncthreads();
    const int base = tid * CH;
    int local[CH];
    int s = 0;
#pragma unroll
    for (int i = 0; i < CH; ++i) {
        local[i] = s;
        s += sdeg[base + i];
    }
    int v = s;
#pragma unroll
    for (int off = 1; off < 64; off <<= 1) {
        const int t = __shfl_up(v, off);
        if (lane >= off) v += t;
    }
    __shared__ int wsum[16];
    if (lane == 63) wsum[wid] = v;
    __syncthreads();
    if (tid == 0) {
        int r = 0;
        for (int i = 0; i < 16; ++i) { const int t = wsum[i]; wsum[i] = r; r += t; }
    }
    __syncthreads();
    const int excl = v - s + wsum[wid];
#pragma unroll
    for (int i = 0; i < CH; ++i) {
        const int idx = base + i;
        if (idx < N_NODES) {
            row_start[idx] = excl + local[i];
            cursor[idx] = 0;
        }
    }
    if (tid == 1023) row_start[N_NODES] = excl + s;
}

__global__ void fill_csr(const int* __restrict__ dst, const int* __restrict__ src,
                         const float* __restrict__ ea,
                         const int* __restrict__ row_start,
                         int* __restrict__ cursor, int2* __restrict__ ekv,
                         float* __restrict__ gstats)
{
    const int g = blockIdx.x * 256 + threadIdx.x;
    if (g < 512) gstats[g] = 0.f;
    const int e = g;
    if (e < N_EDGES) {
        const int d = dst[e];
        const int p = atomicAdd(&cursor[d], 1);
        int2 pk;
        pk.x = src[e];
        pk.y = __float_as_int(ea[e]);
        ekv[row_start[d] + p] = pk;
    }
}

// ---------------- attention: single pass, fp8 k+v (one 8B load/edge/lane) ----------------
static __device__ __forceinline__ void edge_step(const uint2 kv, const float a,
                                                 const float4 qf, const float4 we4,
                                                 float& ssum, float& ax, float& ay,
                                                 float& az, float& aw)
{
    const f32x2 k01 = __builtin_amdgcn_cvt_pk_f32_fp8((int)kv.x, false);
    const f32x2 k23 = __builtin_amdgcn_cvt_pk_f32_fp8((int)kv.x, true);
    const f32x2 v01 = __builtin_amdgcn_cvt_pk_f32_fp8((int)kv.y, false);
    const f32x2 v23 = __builtin_amdgcn_cvt_pk_f32_fp8((int)kv.y, true);
    float p = qf.x * (k01[0] + a * we4.x) + qf.y * (k01[1] + a * we4.y)
            + qf.z * (k23[0] + a * we4.z) + qf.w * (k23[1] + a * we4.w);
    p += __shfl_xor(p, 1); p += __shfl_xor(p, 2);
    p += __shfl_xor(p, 4); p += __shfl_xor(p, 8);
    const float wgt = __expf(p * 0.125f);
    ssum += wgt;
    ax += wgt * (v01[0] + a * we4.x);
    ay += wgt * (v01[1] + a * we4.y);
    az += wgt * (v23[0] + a * we4.z);
    aw += wgt * (v23[1] + a * we4.w);
}

__global__ __launch_bounds__(256) void attn_k(const unsigned short* __restrict__ qb,
                                              const unsigned char* __restrict__ kvb,
                                              const float* __restrict__ We,
                                              const int* __restrict__ row_start,
                                              const int2* __restrict__ ekv,
                                              unsigned short* __restrict__ out)
{
    const int wid  = threadIdx.x >> 6;
    const int lane = threadIdx.x & 63;
    const int n = blockIdx.x * 4 + wid;

    const ushort4 qv = *(const ushort4*)(qb + (size_t)n * 256 + lane * 4);
    float4 qf;
    qf.x = b2f(qv.x); qf.y = b2f(qv.y); qf.z = b2f(qv.z); qf.w = b2f(qv.w);
    const float4 we4 = *(const float4*)(We + lane * 4);
    const int rs = row_start[n], re = row_start[n + 1];
    const int kvo = lane << 3;

    float ssum = 0.f;
    float ax = 0.f, ay = 0.f, az = 0.f, aw = 0.f;

    int s = rs;
    for (; s + 4 <= re; s += 4) {
        const int2 p0 = ekv[s],     p1 = ekv[s + 1];
        const int2 p2 = ekv[s + 2], p3 = ekv[s + 3];
        const uint2 kv0 = *(const uint2*)(kvb + (size_t)p0.x * KVROW + kvo);
        const uint2 kv1 = *(const uint2*)(kvb + (size_t)p1.x * KVROW + kvo);
        const uint2 kv2 = *(const uint2*)(kvb + (size_t)p2.x * KVROW + kvo);
        const uint2 kv3 = *(const uint2*)(kvb + (size_t)p3.x * KVROW + kvo);
        edge_step(kv0, __int_as_float(p0.y), qf, we4, ssum, ax, ay, az, aw);
        edge_step(kv1, __int_as_float(p1.y), qf, we4, ssum, ax, ay, az, aw);
        edge_step(kv2, __int_as_float(p2.y), qf, we4, ssum, ax, ay, az, aw);
        edge_step(kv3, __int_as_float(p3.y), qf, we4, ssum, ax, ay, az, aw);
    }
    for (; s < re; ++s) {
        const int2 p0 = ekv[s];
        const uint2 kv0 = *(const uint2*)(kvb + (size_t)p0.x * KVROW + kvo);
        edge_step(kv0, __int_as_float(p0.y), qf, we4, ssum, ax, ay, az, aw);
    }
    const float inv = 1.f / (ssum + 1e-16f);
    const ushort4 sk4 = *(const ushort4*)(out + (size_t)n * 256 + lane * 4);
    ushort4 ou;
    ou.x = f2bf(ax * inv + b2f(sk4.x));
    ou.y = f2bf(ay * inv + b2f(sk4.y));
    ou.z = f2bf(az * inv + b2f(sk4.z));
    ou.w = f2bf(aw * inv + b2f(sk4.w));
    *(ushort4*)(out + (size_t)n * 256 + lane * 4) = ou;
}

// ---------------- GraphNorm stats (bf16 input) ----------------
__global__ __launch_bounds__(256) void gn_stats_k(const unsigned short* __restrict__ out,
                                                  float* __restrict__ gstats)
{
    const int c = threadIdx.x;
    float s = 0.f, s2 = 0.f;
    for (int r = blockIdx.x; r < N_NODES; r += gridDim.x) {
        const float vv = b2f(out[(size_t)r * 256 + c]);
        s += vv; s2 += vv * vv;
    }
    atomicAdd(&gstats[c], s);
    atomicAdd(&gstats[256 + c], s2);
}

// ---------------- norm + relu + bf16 transpose: obT[256][SK]; also zeroes xt ----------------
__global__ __launch_bounds__(256) void norm_relu_T(const unsigned short* __restrict__ ob,
                                                   const float* __restrict__ gstats,
                                                   const float* __restrict__ gw,
                                                   const float* __restrict__ gb,
                                                   const float* __restrict__ gms,
                                                   unsigned short* __restrict__ obT,
                                                   float* __restrict__ xt)
{
    __shared__ unsigned short tile[256][72];
    __shared__ float smu[256], swi[256], sbd[256];
    const int t = threadIdx.x;
    const int r0 = blockIdx.x * 64;
    {
        const int zi = blockIdx.x * 256 + t;
        if (zi < 65536) xt[zi] = 0.f;
    }
    {
        const float invN = 1.f / (float)N_NODES;
        const float mean = gstats[t] * invN;
        const float exx  = gstats[256 + t] * invN;
        const float mu   = gms[t] * mean;
        const float var  = exx - 2.f * mu * mean + mu * mu;
        smu[t] = mu;
        swi[t] = gw[t] * rsqrtf(var + 1e-5f);
        sbd[t] = gb[t];
    }
    __syncthreads();
    const int rr = t >> 2;
    const int row = r0 + rr;
#pragma unroll
    for (int it = 0; it < 16; ++it) {
        const int col = it * 16 + (t & 3) * 4;
        ushort4 u;
        if (row < N_NODES) {
            const ushort4 uv = *(const ushort4*)(ob + (size_t)row * 256 + col);
            u.x = f2bf(fmaxf((b2f(uv.x) - smu[col + 0]) * swi[col + 0] + sbd[col + 0], 0.f));
            u.y = f2bf(fmaxf((b2f(uv.y) - smu[col + 1]) * swi[col + 1] + sbd[col + 1], 0.f));
            u.z = f2bf(fmaxf((b2f(uv.z) - smu[col + 2]) * swi[col + 2] + sbd[col + 2], 0.f));
            u.w = f2bf(fmaxf((b2f(uv.w) - smu[col + 3]) * swi[col + 3] + sbd[col + 3], 0.f));
        } else { u.x = u.y = u.z = u.w = 0; }
        tile[col + 0][rr] = u.x;
        tile[col + 1][rr] = u.y;
        tile[col + 2][rr] = u.z;
        tile[col + 3][rr] = u.w;
    }
    __syncthreads();
#pragma unroll
    for (int it = 0; it < 8; ++it) {
        const int c = it * 32 + (t >> 3);
        const int part = t & 7;
        const uint4 x0 = *(const uint4*)&tile[c][part * 8];
        *(uint4*)(obT + (size_t)c * SK + r0 + part * 8) = x0;
    }
}

// ---------------- Gram: xt = P^T P via bf16 MFMA on obT, pipelined chunks ----------------
__global__ __launch_bounds__(256) void gram_k(const unsigned short* __restrict__ obT,
                                              float* __restrict__ xt)
{
    const int bi_l[10] = {0,0,0,0,1,1,1,2,2,3};
    const int bj_l[10] = {0,1,2,3,1,2,3,2,3,3};
    const int bi = bi_l[blockIdx.x], bj = bj_l[blockIdx.x];
    const int r0 = blockIdx.y * 256;

    __shared__ __align__(16) unsigned short Ai[64 * GPITCH];
    __shared__ __align__(16) unsigned short Aj[64 * GPITCH];
    const int tid = threadIdx.x;
    const int lane = tid & 63;
    const int w = tid >> 6;
    const int wi = w >> 1, wj = w & 1;
    const int lr = tid >> 2, kseg = (tid & 3) * 32;
    const int fr = lane & 15, fk = (lane >> 4) * 8, lg = lane >> 4;

    f32x4 acc[2][2] = {};

    const unsigned short* pa = obT + (size_t)(bi * 64 + lr) * SK + r0 + kseg;
    const unsigned short* pb = obT + (size_t)(bj * 64 + lr) * SK + r0 + kseg;
    uint4 ai[4], aj[4];
#pragma unroll
    for (int j = 0; j < 4; ++j) { ai[j] = *(const uint4*)(pa + 8 * j); aj[j] = *(const uint4*)(pb + 8 * j); }

#pragma unroll
    for (int itr = 0; itr < 2; ++itr) {
        __syncthreads();
#pragma unroll
        for (int j = 0; j < 4; ++j) {
            *(uint4*)&Ai[lr * GPITCH + kseg + 8 * j] = ai[j];
            *(uint4*)&Aj[lr * GPITCH + kseg + 8 * j] = aj[j];
        }
        __syncthreads();
        if (itr == 0) {
#pragma unroll
            for (int j = 0; j < 4; ++j) {
                ai[j] = *(const uint4*)(pa + 128 + 8 * j);
                aj[j] = *(const uint4*)(pb + 128 + 8 * j);
            }
        }
#pragma unroll
        for (int ks = 0; ks < 4; ++ks) {
            short8 af[2], bf[2];
#pragma unroll
            for (int m = 0; m < 2; ++m)
                af[m] = *(const short8*)&Ai[(wi * 32 + m * 16 + fr) * GPITCH + ks * 32 + fk];
#pragma unroll
            for (int n = 0; n < 2; ++n)
                bf[n] = *(const short8*)&Aj[(wj * 32 + n * 16 + fr) * GPITCH + ks * 32 + fk];
#pragma unroll
            for (int m = 0; m < 2; ++m)
#pragma unroll
                for (int n = 0; n < 2; ++n)
                    acc[m][n] = __builtin_amdgcn_mfma_f32_16x16x32_bf16(af[m], bf[n], acc[m][n], 0, 0, 0);
        }
    }
#pragma unroll
    for (int m = 0; m < 2; ++m)
#pragma unroll
        for (int n = 0; n < 2; ++n)
#pragma unroll
            for (int r = 0; r < 4; ++r)
                atomicAdd(&xt[(size_t)(bi * 64 + wi * 32 + m * 16 + lg * 4 + r) * 256
                              + bj * 64 + wj * 32 + n * 16 + fr], acc[m][n][r]);
}

// ---------------- fused min/max + finalize (single block) ----------------
__global__ __launch_bounds__(1024) void minmax_fin_k(const float* __restrict__ xt,
                                                     float* __restrict__ outp)
{
    const int tid = threadIdx.x;
    float mn = 1e30f, mx = -1e30f;
    for (int i = tid; i < 65536; i += 1024) {
        const int r = i >> 8, c = i & 255;
        if ((r >> 6) <= (c >> 6)) {
            const float v = xt[i];
            mn = fminf(mn, v);
            mx = fmaxf(mx, v);
        }
    }
    for (int off = 1; off < 64; off <<= 1) {
        mn = fminf(mn, __shfl_xor(mn, off));
        mx = fmaxf(mx, __shfl_xor(mx, off));
    }
    __shared__ float smn[16], smx[16];
    __shared__ float fmn, fmx;
    const int w = tid >> 6;
    if ((tid & 63) == 0) { smn[w] = mn; smx[w] = mx; }
    __syncthreads();
    if (tid == 0) {
        for (int i = 1; i < 16; ++i) {
            mn = fminf(mn, smn[i]);
            mx = fmaxf(mx, smx[i]);
        }
        fmn = mn; fmx = mx;
    }
    __syncthreads();
    const float gmn = fmn;
    const float inv = 1.f / (fmx - gmn + 1e-8f);
    for (int i = tid; i < 65536; i += 1024) {
        const int r = i >> 8, c = i & 255;
        const float v = ((r >> 6) <= (c >> 6)) ? xt[i] : xt[c * 256 + r];
        outp[i] = (v - gmn) * inv;
    }
}

// ---------------- launch ----------------
extern "C" void kernel_launch(void* const* d_in, const int* in_sizes, int n_in,
                              void* d_out, int out_size, void* d_ws, size_t ws_size,
                              hipStream_t stream)
{
    (void)in_sizes; (void)n_in; (void)out_size; (void)ws_size;
    const float* x   = (const float*)d_in[0];
    const int*   ei  = (const int*)d_in[1];
    const float* ea  = (const float*)d_in[2];
    const float* Wq  = (const float*)d_in[3];
    const float* bq  = (const float*)d_in[4];
    const float* Wk  = (const float*)d_in[5];
    const float* bk  = (const float*)d_in[6];
    const float* Wv  = (const float*)d_in[7];
    const float* bv  = (const float*)d_in[8];
    const float* We  = (const float*)d_in[9];
    const float* Wsk = (const float*)d_in[10];
    const float* bsk = (const float*)d_in[11];
    const float* gw  = (const float*)d_in[12];
    const float* gb  = (const float*)d_in[13];
    const float* gms = (const float*)d_in[14];
    float* outp = (float*)d_out;

    char* ws = (char*)d_ws;
    size_t off = 0;
    #define WS_ALLOC(nbytes) (ws + off); off = (off + (size_t)(nbytes) + 255) & ~(size_t)255
    unsigned short* xb  = (unsigned short*)WS_ALLOC((size_t)N_NODES * 256 * 2);   // dead after gemm
    unsigned short* wT  = (unsigned short*)WS_ALLOC((size_t)1024 * 256 * 2);      // dead after gemm
    float* bias_all     = (float*)WS_ALLOC(1024 * 4);                             // dead after gemm
    unsigned short* qb  = (unsigned short*)WS_ALLOC((size_t)N_NODES * 256 * 2);   // bf16 q
    unsigned char*  kvb = (unsigned char*)WS_ALLOC((size_t)N_NODES * KVROW);      // fp8 k|v interleaved
    unsigned short* ob  = (unsigned short*)WS_ALLOC((size_t)N_NODES * 256 * 2);   // bf16 skip->out
    int*   deg          = (int*)WS_ALLOC((size_t)N_NODES * 4);                    // zeroed by prep_k
    int*   cur          = (int*)WS_ALLOC((size_t)N_NODES * 4);                    // zeroed by scan_k
    float* gstats       = (float*)WS_ALLOC(512 * 4);                              // zeroed by fill_csr
    float* xt           = (float*)WS_ALLOC(65536 * 4);                            // zeroed by norm_relu_T
    int* row_start      = (int*)WS_ALLOC((size_t)(N_NODES + 1) * 4);
    #undef WS_ALLOC
    // overlays rooted at xb (disjoint lifetimes)
    int2* ekv           = (int2*)xb;
    unsigned short* obT = (unsigned short*)xb;

    const int* srcv = ei;            // edge_index[0]
    const int* dstv = ei + N_EDGES;  // edge_index[1]

    prep_k<<<2500 + 64 + 79, 256, 0, stream>>>(x, xb, Wq, Wk, Wv, Wsk,
                                               bq, bk, bv, bsk, wT, bias_all, deg);

    gemm_qkvs<<<dim3(157, 9), 256, 0, stream>>>(xb, wT, bias_all,
                                                qb, kvb, ob, dstv, deg);

    scan_k<<<1, 1024, 0, stream>>>(deg, row_start, cur);
    fill_csr<<<(N_EDGES + 255) / 256, 256, 0, stream>>>(dstv, srcv, ea, row_start,
                                                        cur, ekv, gstats);

    attn_k<<<N_NODES / 4, 256, 0, stream>>>(qb, kvb, We, row_start, ekv, ob);

    gn_stats_k<<<400, 256, 0, stream>>>(ob, gstats);
    norm_relu_T<<<320, 256, 0, stream>>>(ob, gstats, gw, gb, gms, obT, xt);

    gram_k<<<dim3(10, 80), 256, 0, stream>>>(obT, xt);
    minmax_fin_k<<<1, 1024, 0, stream>>>(xt, outp);
}

// Round 20
// 208.695 us; speedup vs baseline: 1.1103x; 1.0039x over previous
//
#include <hip/hip_runtime.h>
#include <math.h>

#define N_NODES 20000
#define N_EDGES 320000
#define SK 20480   // zero-padded K (rows) for transposed gram operand
#define APAD 72    // gemm LDS pitch: 36 words -> uniform bank map (reads & writes), 16B-aligned
#define GPITCH 144 // gram LDS pitch (elems)
#define KVROW 512  // kv row bytes: 64 chunks x [k fp8 4B | v fp8 4B]

typedef short short8 __attribute__((ext_vector_type(8)));
typedef float f32x4 __attribute__((ext_vector_type(4)));
typedef float f32x2 __attribute__((ext_vector_type(2)));

static __device__ __forceinline__ unsigned short f2bf(float f) {
    unsigned int u = __float_as_uint(f);
    u = (u + 0x7FFF + ((u >> 16) & 1)) >> 16;
    return (unsigned short)u;
}
static __device__ __forceinline__ float b2f(unsigned short u) {
    return __uint_as_float((unsigned int)u << 16);
}

// ---------------- fused prep: conv_x (2500) | conv_w LDS-transpose (64) | zero deg (79) ----------------
__global__ __launch_bounds__(256) void prep_k(const float* __restrict__ x,
                                              unsigned short* __restrict__ xb,
                                              const float* __restrict__ Wq,
                                              const float* __restrict__ Wk,
                                              const float* __restrict__ Wv,
                                              const float* __restrict__ Wsk,
                                              const float* __restrict__ bq,
                                              const float* __restrict__ bk,
                                              const float* __restrict__ bv,
                                              const float* __restrict__ bsk,
                                              unsigned short* __restrict__ wT,
                                              float* __restrict__ bias_all,
                                              int* __restrict__ deg)
{
    __shared__ float tw[64][65];       // pitch 65 -> conflict-free transpose
    const int b = blockIdx.x;
    const int tid = threadIdx.x;
    if (b < 2500) {
        const size_t base = ((size_t)b * 256 + tid) * 8;
        const float4 f0 = *(const float4*)(x + base);
        const float4 f1 = *(const float4*)(x + base + 4);
        ushort4 u0, u1;
        u0.x = f2bf(f0.x); u0.y = f2bf(f0.y); u0.z = f2bf(f0.z); u0.w = f2bf(f0.w);
        u1.x = f2bf(f1.x); u1.y = f2bf(f1.y); u1.z = f2bf(f1.z); u1.w = f2bf(f1.w);
        *(ushort4*)(xb + base) = u0;
        *(ushort4*)(xb + base + 4) = u1;
    } else if (b < 2564) {
        const int b2 = b - 2500;               // 0..63
        const int wi = b2 >> 4;
        const int t2 = b2 & 15;
        const int n0 = (t2 & 3) * 64;
        const int k0 = (t2 >> 2) * 64;
        const float* W = (wi == 0) ? Wq : (wi == 1) ? Wk : (wi == 2) ? Wv : Wsk;
        const int r = tid >> 6, c = tid & 63;
#pragma unroll
        for (int it = 0; it < 16; ++it) {
            const int row = it * 4 + r;
            tw[row][c] = W[(size_t)(k0 + row) * 256 + n0 + c];
        }
        __syncthreads();
#pragma unroll
        for (int it = 0; it < 16; ++it) {
            const int n = it * 4 + r;
            wT[(size_t)(wi * 256 + n0 + n) * 256 + k0 + c] = f2bf(tw[c][n]);
        }
        if (k0 == 0 && tid < 64) {
            const float* bv_ = (wi == 0) ? bq : (wi == 1) ? bk : (wi == 2) ? bv : bsk;
            bias_all[wi * 256 + n0 + tid] = bv_[n0 + tid];
        }
    } else {
        const int i = (b - 2564) * 256 + tid;
        if (i < N_NODES) deg[i] = 0;
    }
}

// ---------------- fused QKVS GEMM (pipelined LDS) + count_deg plane ----------------
__global__ __launch_bounds__(256, 4) void gemm_qkvs(const unsigned short* __restrict__ xb,
                                                    const unsigned short* __restrict__ wT,
                                                    const float* __restrict__ bias_all,
                                                    unsigned short* __restrict__ qb,
                                                    unsigned char* __restrict__ kvb,
                                                    unsigned short* __restrict__ ob,
                                                    const int* __restrict__ dst,
                                                    int* __restrict__ deg)
{
    const int tid  = threadIdx.x;
    const int by   = blockIdx.y;
    if (by == 8) {                     // degree count (deg zeroed by prep_k)
        for (int e = blockIdx.x * 256 + tid; e < N_EDGES; e += 157 * 256)
            atomicAdd(&deg[dst[e]], 1);
        return;
    }

    __shared__ __align__(16) unsigned short As[(128 + 128) * APAD];
    unsigned short* Bs = As + 128 * APAD;
    float* stage = (float*)As;

    const int lane = tid & 63;
    const int w    = tid >> 6;
    const int wm = w >> 1, wn = w & 1;
    const int row0 = blockIdx.x * 128;
    const int wsel = by >> 1;          // 0=q 1=k 2=v 3=skip
    const int ar = tid >> 1, ak = (tid & 1) * 32;
    const int fr = lane & 15, fk = (lane >> 4) * 8, lg = lane >> 4;

    int gr = row0 + ar; gr = gr < N_NODES ? gr : N_NODES - 1;
    const unsigned short* ab = xb + (size_t)gr * 256 + ak;
    const unsigned short* bb = wT + (size_t)(by * 128 + ar) * 256 + ak;

    f32x4 acc[4][4] = {};
    uint4 a0, a1, a2, a3, b0, b1, b2, b3;

    a0 = *(const uint4*)ab;        a1 = *(const uint4*)(ab + 8);
    a2 = *(const uint4*)(ab + 16); a3 = *(const uint4*)(ab + 24);
    b0 = *(const uint4*)bb;        b1 = *(const uint4*)(bb + 8);
    b2 = *(const uint4*)(bb + 16); b3 = *(const uint4*)(bb + 24);

#pragma unroll
    for (int it = 0; it < 4; ++it) {
        __syncthreads();
        unsigned short* asp = &As[ar * APAD + ak];
        *(uint4*)asp        = a0;
        *(uint4*)(asp + 8)  = a1;
        *(uint4*)(asp + 16) = a2;
        *(uint4*)(asp + 24) = a3;
        unsigned short* bsp = &Bs[ar * APAD + ak];
        *(uint4*)bsp        = b0;
        *(uint4*)(bsp + 8)  = b1;
        *(uint4*)(bsp + 16) = b2;
        *(uint4*)(bsp + 24) = b3;
        __syncthreads();
        if (it < 3) {
            const unsigned short* ap = ab + (it + 1) * 64;
            const unsigned short* bp = bb + (it + 1) * 64;
            a0 = *(const uint4*)ap;        a1 = *(const uint4*)(ap + 8);
            a2 = *(const uint4*)(ap + 16); a3 = *(const uint4*)(ap + 24);
            b0 = *(const uint4*)bp;        b1 = *(const uint4*)(bp + 8);
            b2 = *(const uint4*)(bp + 16); b3 = *(const uint4*)(bp + 24);
        }
#pragma unroll
        for (int ks = 0; ks < 2; ++ks) {
            short8 af[4], bf[4];
#pragma unroll
            for (int m = 0; m < 4; ++m)
                af[m] = *(const short8*)&As[(wm * 64 + m * 16 + fr) * APAD + ks * 32 + fk];
#pragma unroll
            for (int n = 0; n < 4; ++n)
                bf[n] = *(const short8*)&Bs[(wn * 64 + n * 16 + fr) * APAD + ks * 32 + fk];
#pragma unroll
            for (int m = 0; m < 4; ++m)
#pragma unroll
                for (int n = 0; n < 4; ++n)
                    acc[m][n] = __builtin_amdgcn_mfma_f32_16x16x32_bf16(af[m], bf[n], acc[m][n], 0, 0, 0);
        }
    }
    __syncthreads();

    float badd[4];
#pragma unroll
    for (int n = 0; n < 4; ++n) badd[n] = bias_all[by * 128 + wn * 64 + n * 16 + fr];

    float* st = stage + w * 1024;
    const int chalf = by & 1;
#pragma unroll
    for (int m = 0; m < 4; ++m) {
#pragma unroll
        for (int n = 0; n < 4; ++n)
#pragma unroll
            for (int r = 0; r < 4; ++r)
                st[(lg * 4 + r) * 64 + n * 16 + fr] = acc[m][n][r] + badd[n];
#pragma unroll
        for (int it = 0; it < 4; ++it) {
            const int lrow = it * 4 + lg;
            const f32x4 c4 = *(const f32x4*)&st[lrow * 64 + fr * 4];
            const int grow = row0 + wm * 64 + m * 16 + lrow;
            if (grow < N_NODES) {
                const int colin = chalf * 128 + wn * 64 + fr * 4;
                if (wsel == 1 || wsel == 2) {
                    int pk = __builtin_amdgcn_cvt_pk_fp8_f32(c4[0], c4[1], 0, false);
                    pk = __builtin_amdgcn_cvt_pk_fp8_f32(c4[2], c4[3], pk, true);
                    const int c = chalf * 32 + wn * 16 + fr;
                    *(unsigned int*)(kvb + (size_t)grow * KVROW + c * 8 + (wsel == 1 ? 0 : 4))
                        = (unsigned int)pk;
                } else {
                    ushort4 u;
                    u.x = f2bf(c4[0]); u.y = f2bf(c4[1]); u.z = f2bf(c4[2]); u.w = f2bf(c4[3]);
                    if (wsel == 3) *(ushort4*)(ob + (size_t)grow * 256 + colin) = u;
                    else           *(ushort4*)(qb + (size_t)grow * 256 + colin) = u;
                }
            }
        }
    }
}

// ---------------- CSR scan (coalesced staging; also zeroes cursor) ----------------
__global__ __launch_bounds__(1024) void scan_k(const int* __restrict__ deg,
                                               int* __restrict__ row_start,
                                               int* __restrict__ cursor)
{
    __shared__ int sdeg[20480];
    const int tid = threadIdx.x;
    const int lane = tid & 63, wid = tid >> 6;
    const int CH = 20;
#pragma unroll
    for (int i = 0; i < 20; ++i) {
        const int idx = i * 1024 + tid;
        sdeg[idx] = (idx < N_NODES) ? deg[idx] : 0;
    }
    __syncthreads();
    const int base = tid * CH;
    int local[CH];
    int s = 0;
#pragma unroll
    for (int i = 0; i < CH; ++i) {
        local[i] = s;
        s += sdeg[base + i];
    }
    int v = s;
#pragma unroll
    for (int off = 1; off < 64; off <<= 1) {
        const int t = __shfl_up(v, off);
        if (lane >= off) v += t;
    }
    __shared__ int wsum[16];
    if (lane == 63) wsum[wid] = v;
    __syncthreads();
    if (tid == 0) {
        int r = 0;
        for (int i = 0; i < 16; ++i) { const int t = wsum[i]; wsum[i] = r; r += t; }
    }
    __syncthreads();
    const int excl = v - s + wsum[wid];
#pragma unroll
    for (int i = 0; i < CH; ++i) {
        const int idx = base + i;
        if (idx < N_NODES) {
            row_start[idx] = excl + local[i];
            cursor[idx] = 0;
        }
    }
    if (tid == 1023) row_start[N_NODES] = excl + s;
}

__global__ void fill_csr(const int* __restrict__ dst, const int* __restrict__ src,
                         const float* __restrict__ ea,
                         const int* __restrict__ row_start,
                         int* __restrict__ cursor, int2* __restrict__ ekv,
                         float* __restrict__ gstats)
{
    const int g = blockIdx.x * 256 + threadIdx.x;
    if (g < 512) gstats[g] = 0.f;
    const int e = g;
    if (e < N_EDGES) {
        const int d = dst[e];
        const int p = atomicAdd(&cursor[d], 1);
        int2 pk;
        pk.x = src[e];
        pk.y = __float_as_int(ea[e]);
        ekv[row_start[d] + p] = pk;
    }
}

// ---------------- attention: single pass, fp8 k+v (one 8B load/edge/lane) ----------------
static __device__ __forceinline__ void edge_step(const uint2 kv, const float a,
                                                 const float4 qf, const float4 we4,
                                                 float& ssum, float& ax, float& ay,
                                                 float& az, float& aw)
{
    const f32x2 k01 = __builtin_amdgcn_cvt_pk_f32_fp8((int)kv.x, false);
    const f32x2 k23 = __builtin_amdgcn_cvt_pk_f32_fp8((int)kv.x, true);
    const f32x2 v01 = __builtin_amdgcn_cvt_pk_f32_fp8((int)kv.y, false);
    const f32x2 v23 = __builtin_amdgcn_cvt_pk_f32_fp8((int)kv.y, true);
    float p = qf.x * (k01[0] + a * we4.x) + qf.y * (k01[1] + a * we4.y)
            + qf.z * (k23[0] + a * we4.z) + qf.w * (k23[1] + a * we4.w);
    p += __shfl_xor(p, 1); p += __shfl_xor(p, 2);
    p += __shfl_xor(p, 4); p += __shfl_xor(p, 8);
    const float wgt = __expf(p * 0.125f);
    ssum += wgt;
    ax += wgt * (v01[0] + a * we4.x);
    ay += wgt * (v01[1] + a * we4.y);
    az += wgt * (v23[0] + a * we4.z);
    aw += wgt * (v23[1] + a * we4.w);
}

__global__ __launch_bounds__(256) void attn_k(const unsigned short* __restrict__ qb,
                                              const unsigned char* __restrict__ kvb,
                                              const float* __restrict__ We,
                                              const int* __restrict__ row_start,
                                              const int2* __restrict__ ekv,
                                              unsigned short* __restrict__ out)
{
    const int wid  = threadIdx.x >> 6;
    const int lane = threadIdx.x & 63;
    const int n = blockIdx.x * 4 + wid;

    const ushort4 qv = *(const ushort4*)(qb + (size_t)n * 256 + lane * 4);
    float4 qf;
    qf.x = b2f(qv.x); qf.y = b2f(qv.y); qf.z = b2f(qv.z); qf.w = b2f(qv.w);
    const float4 we4 = *(const float4*)(We + lane * 4);
    const int rs = row_start[n], re = row_start[n + 1];
    const int kvo = lane << 3;

    float ssum = 0.f;
    float ax = 0.f, ay = 0.f, az = 0.f, aw = 0.f;

    int s = rs;
    for (; s + 4 <= re; s += 4) {
        const int2 p0 = ekv[s],     p1 = ekv[s + 1];
        const int2 p2 = ekv[s + 2], p3 = ekv[s + 3];
        const uint2 kv0 = *(const uint2*)(kvb + (size_t)p0.x * KVROW + kvo);
        const uint2 kv1 = *(const uint2*)(kvb + (size_t)p1.x * KVROW + kvo);
        const uint2 kv2 = *(const uint2*)(kvb + (size_t)p2.x * KVROW + kvo);
        const uint2 kv3 = *(const uint2*)(kvb + (size_t)p3.x * KVROW + kvo);
        edge_step(kv0, __int_as_float(p0.y), qf, we4, ssum, ax, ay, az, aw);
        edge_step(kv1, __int_as_float(p1.y), qf, we4, ssum, ax, ay, az, aw);
        edge_step(kv2, __int_as_float(p2.y), qf, we4, ssum, ax, ay, az, aw);
        edge_step(kv3, __int_as_float(p3.y), qf, we4, ssum, ax, ay, az, aw);
    }
    for (; s < re; ++s) {
        const int2 p0 = ekv[s];
        const uint2 kv0 = *(const uint2*)(kvb + (size_t)p0.x * KVROW + kvo);
        edge_step(kv0, __int_as_float(p0.y), qf, we4, ssum, ax, ay, az, aw);
    }
    const float inv = 1.f / (ssum + 1e-16f);
    const ushort4 sk4 = *(const ushort4*)(out + (size_t)n * 256 + lane * 4);
    ushort4 ou;
    ou.x = f2bf(ax * inv + b2f(sk4.x));
    ou.y = f2bf(ay * inv + b2f(sk4.y));
    ou.z = f2bf(az * inv + b2f(sk4.z));
    ou.w = f2bf(aw * inv + b2f(sk4.w));
    *(ushort4*)(out + (size_t)n * 256 + lane * 4) = ou;
}

// ---------------- GraphNorm stats (bf16 input) ----------------
__global__ __launch_bounds__(256) void gn_stats_k(const unsigned short* __restrict__ out,
                                                  float* __restrict__ gstats)
{
    const int c = threadIdx.x;
    float s = 0.f, s2 = 0.f;
    for (int r = blockIdx.x; r < N_NODES; r += gridDim.x) {
        const float vv = b2f(out[(size_t)r * 256 + c]);
        s += vv; s2 += vv * vv;
    }
    atomicAdd(&gstats[c], s);
    atomicAdd(&gstats[256 + c], s2);
}

// ---------------- norm + relu + bf16 transpose: obT[256][SK]; also zeroes xt ----------------
__global__ __launch_bounds__(256) void norm_relu_T(const unsigned short* __restrict__ ob,
                                                   const float* __restrict__ gstats,
                                                   const float* __restrict__ gw,
                                                   const float* __restrict__ gb,
                                                   const float* __restrict__ gms,
                                                   unsigned short* __restrict__ obT,
                                                   float* __restrict__ xt)
{
    __shared__ unsigned short tile[256][72];
    __shared__ float smu[256], swi[256], sbd[256];
    const int t = threadIdx.x;
    const int r0 = blockIdx.x * 64;
    {
        const int zi = blockIdx.x * 256 + t;
        if (zi < 65536) xt[zi] = 0.f;
    }
    {
        const float invN = 1.f / (float)N_NODES;
        const float mean = gstats[t] * invN;
        const float exx  = gstats[256 + t] * invN;
        const float mu   = gms[t] * mean;
        const float var  = exx - 2.f * mu * mean + mu * mu;
        smu[t] = mu;
        swi[t] = gw[t] * rsqrtf(var + 1e-5f);
        sbd[t] = gb[t];
    }
    __syncthreads();
    const int rr = t >> 2;
    const int row = r0 + rr;
#pragma unroll
    for (int it = 0; it < 16; ++it) {
        const int col = it * 16 + (t & 3) * 4;
        ushort4 u;
        if (row < N_NODES) {
            const ushort4 uv = *(const ushort4*)(ob + (size_t)row * 256 + col);
            u.x = f2bf(fmaxf((b2f(uv.x) - smu[col + 0]) * swi[col + 0] + sbd[col + 0], 0.f));
            u.y = f2bf(fmaxf((b2f(uv.y) - smu[col + 1]) * swi[col + 1] + sbd[col + 1], 0.f));
            u.z = f2bf(fmaxf((b2f(uv.z) - smu[col + 2]) * swi[col + 2] + sbd[col + 2], 0.f));
            u.w = f2bf(fmaxf((b2f(uv.w) - smu[col + 3]) * swi[col + 3] + sbd[col + 3], 0.f));
        } else { u.x = u.y = u.z = u.w = 0; }
        tile[col + 0][rr] = u.x;
        tile[col + 1][rr] = u.y;
        tile[col + 2][rr] = u.z;
        tile[col + 3][rr] = u.w;
    }
    __syncthreads();
#pragma unroll
    for (int it = 0; it < 8; ++it) {
        const int c = it * 32 + (t >> 3);
        const int part = t & 7;
        const uint4 x0 = *(const uint4*)&tile[c][part * 8];
        *(uint4*)(obT + (size_t)c * SK + r0 + part * 8) = x0;
    }
}

// ---------------- Gram: xt = P^T P via bf16 MFMA on obT, pipelined chunks ----------------
__global__ __launch_bounds__(256) void gram_k(const unsigned short* __restrict__ obT,
                                              float* __restrict__ xt)
{
    const int bi_l[10] = {0,0,0,0,1,1,1,2,2,3};
    const int bj_l[10] = {0,1,2,3,1,2,3,2,3,3};
    const int bi = bi_l[blockIdx.x], bj = bj_l[blockIdx.x];
    const int r0 = blockIdx.y * 256;

    __shared__ __align__(16) unsigned short Ai[64 * GPITCH];
    __shared__ __align__(16) unsigned short Aj[64 * GPITCH];
    const int tid = threadIdx.x;
    const int lane = tid & 63;
    const int w = tid >> 6;
    const int wi = w >> 1, wj = w & 1;
    const int lr = tid >> 2, kseg = (tid & 3) * 32;
    const int fr = lane & 15, fk = (lane >> 4) * 8, lg = lane >> 4;

    f32x4 acc[2][2] = {};

    const unsigned short* pa = obT + (size_t)(bi * 64 + lr) * SK + r0 + kseg;
    const unsigned short* pb = obT + (size_t)(bj * 64 + lr) * SK + r0 + kseg;
    uint4 ai[4], aj[4];
#pragma unroll
    for (int j = 0; j < 4; ++j) { ai[j] = *(const uint4*)(pa + 8 * j); aj[j] = *(const uint4*)(pb + 8 * j); }

#pragma unroll
    for (int itr = 0; itr < 2; ++itr) {
        __syncthreads();
#pragma unroll
        for (int j = 0; j < 4; ++j) {
            *(uint4*)&Ai[lr * GPITCH + kseg + 8 * j] = ai[j];
            *(uint4*)&Aj[lr * GPITCH + kseg + 8 * j] = aj[j];
        }
        __syncthreads();
        if (itr == 0) {
#pragma unroll
            for (int j = 0; j < 4; ++j) {
                ai[j] = *(const uint4*)(pa + 128 + 8 * j);
                aj[j] = *(const uint4*)(pb + 128 + 8 * j);
            }
        }
#pragma unroll
        for (int ks = 0; ks < 4; ++ks) {
            short8 af[2], bf[2];
#pragma unroll
            for (int m = 0; m < 2; ++m)
                af[m] = *(const short8*)&Ai[(wi * 32 + m * 16 + fr) * GPITCH + ks * 32 + fk];
#pragma unroll
            for (int n = 0; n < 2; ++n)
                bf[n] = *(const short8*)&Aj[(wj * 32 + n * 16 + fr) * GPITCH + ks * 32 + fk];
#pragma unroll
            for (int m = 0; m < 2; ++m)
#pragma unroll
                for (int n = 0; n < 2; ++n)
                    acc[m][n] = __builtin_amdgcn_mfma_f32_16x16x32_bf16(af[m], bf[n], acc[m][n], 0, 0, 0);
        }
    }
#pragma unroll
    for (int m = 0; m < 2; ++m)
#pragma unroll
        for (int n = 0; n < 2; ++n)
#pragma unroll
            for (int r = 0; r < 4; ++r)
                atomicAdd(&xt[(size_t)(bi * 64 + wi * 32 + m * 16 + lg * 4 + r) * 256
                              + bj * 64 + wj * 32 + n * 16 + fr], acc[m][n][r]);
}

// ---------------- fused min/max + finalize (single block) ----------------
__global__ __launch_bounds__(1024) void minmax_fin_k(const float* __restrict__ xt,
                                                     float* __restrict__ outp)
{
    const int tid = threadIdx.x;
    float mn = 1e30f, mx = -1e30f;
    for (int i = tid; i < 65536; i += 1024) {
        const int r = i >> 8, c = i & 255;
        if ((r >> 6) <= (c >> 6)) {
            const float v = xt[i];
            mn = fminf(mn, v);
            mx = fmaxf(mx, v);
        }
    }
    for (int off = 1; off < 64; off <<= 1) {
        mn = fminf(mn, __shfl_xor(mn, off));
        mx = fmaxf(mx, __shfl_xor(mx, off));
    }
    __shared__ float smn[16], smx[16];
    __shared__ float fmn, fmx;
    const int w = tid >> 6;
    if ((tid & 63) == 0) { smn[w] = mn; smx[w] = mx; }
    __syncthreads();
    if (tid == 0) {
        for (int i = 1; i < 16; ++i) {
            mn = fminf(mn, smn[i]);
            mx = fmaxf(mx, smx[i]);
        }
        fmn = mn; fmx = mx;
    }
    __syncthreads();
    const float gmn = fmn;
    const float inv = 1.f / (fmx - gmn + 1e-8f);
    for (int i = tid; i < 65536; i += 1024) {
        const int r = i >> 8, c = i & 255;
        const float v = ((r >> 6) <= (c >> 6)) ? xt[i] : xt[c * 256 + r];
        outp[i] = (v - gmn) * inv;
    }
}

// ---------------- launch ----------------
extern "C" void kernel_launch(void* const* d_in, const int* in_sizes, int n_in,
                              void* d_out, int out_size, void* d_ws, size_t ws_size,
                              hipStream_t stream)
{
    (void)in_sizes; (void)n_in; (void)out_size; (void)ws_size;
    const float* x   = (const float*)d_in[0];
    const int*   ei  = (const int*)d_in[1];
    const float* ea  = (const float*)d_in[2];
    const float* Wq  = (const float*)d_in[3];
    const float* bq  = (const float*)d_in[4];
    const float* Wk  = (const float*)d_in[5];
    const float* bk  = (const float*)d_in[6];
    const float* Wv  = (const float*)d_in[7];
    const float* bv  = (const float*)d_in[8];
    const float* We  = (const float*)d_in[9];
    const float* Wsk = (const float*)d_in[10];
    const float* bsk = (const float*)d_in[11];
    const float* gw  = (const float*)d_in[12];
    const float* gb  = (const float*)d_in[13];
    const float* gms = (const float*)d_in[14];
    float* outp = (float*)d_out;

    char* ws = (char*)d_ws;
    size_t off = 0;
    #define WS_ALLOC(nbytes) (ws + off); off = (off + (size_t)(nbytes) + 255) & ~(size_t)255
    unsigned short* xb  = (unsigned short*)WS_ALLOC((size_t)N_NODES * 256 * 2);   // dead after gemm
    unsigned short* wT  = (unsigned short*)WS_ALLOC((size_t)1024 * 256 * 2);      // dead after gemm
    float* bias_all     = (float*)WS_ALLOC(1024 * 4);                             // dead after gemm
    unsigned short* qb  = (unsigned short*)WS_ALLOC((size_t)N_NODES * 256 * 2);   // bf16 q
    unsigned char*  kvb = (unsigned char*)WS_ALLOC((size_t)N_NODES * KVROW);      // fp8 k|v interleaved
    unsigned short* ob  = (unsigned short*)WS_ALLOC((size_t)N_NODES * 256 * 2);   // bf16 skip->out
    int*   deg          = (int*)WS_ALLOC((size_t)N_NODES * 4);                    // zeroed by prep_k
    int*   cur          = (int*)WS_ALLOC((size_t)N_NODES * 4);                    // zeroed by scan_k
    float* gstats       = (float*)WS_ALLOC(512 * 4);                              // zeroed by fill_csr
    float* xt           = (float*)WS_ALLOC(65536 * 4);                            // zeroed by norm_relu_T
    int* row_start      = (int*)WS_ALLOC((size_t)(N_NODES + 1) * 4);
    #undef WS_ALLOC
    // overlays rooted at xb (disjoint lifetimes)
    int2* ekv           = (int2*)xb;
    unsigned short* obT = (unsigned short*)xb;

    const int* srcv = ei;            // edge_index[0]
    const int* dstv = ei + N_EDGES;  // edge_index[1]

    prep_k<<<2500 + 64 + 79, 256, 0, stream>>>(x, xb, Wq, Wk, Wv, Wsk,
                                               bq, bk, bv, bsk, wT, bias_all, deg);

    gemm_qkvs<<<dim3(157, 9), 256, 0, stream>>>(xb, wT, bias_all,
                                                qb, kvb, ob, dstv, deg);

    scan_k<<<1, 1024, 0, stream>>>(deg, row_start, cur);
    fill_csr<<<(N_EDGES + 255) / 256, 256, 0, stream>>>(dstv, srcv, ea, row_start,
                                                        cur, ekv, gstats);

    attn_k<<<N_NODES / 4, 256, 0, stream>>>(qb, kvb, We, row_start, ekv, ob);

    gn_stats_k<<<400, 256, 0, stream>>>(ob, gstats);
    norm_relu_T<<<320, 256, 0, stream>>>(ob, gstats, gw, gb, gms, obT, xt);

    gram_k<<<dim3(10, 80), 256, 0, stream>>>(obT, xt);
    minmax_fin_k<<<1, 1024, 0, stream>>>(xt, outp);
}